// Round 9
// baseline (619.553 us; speedup 1.0000x reference)
//
#include <hip/hip_runtime.h>

// ChebNet K=3. Zero global atomics:
//  - hist: per-(copy,range)-exclusive LDS histograms (cnt8 + deg8), plain-store flush
//  - build: LDS cursors per (copy,range), dense per-block arena regions
//  - props: gather-side CSR, 8 loads in flight
// copy of edge e = (e>>8)&7 everywhere (piece = 256 edges).

#define BS 256
#define NC 8      // copies (= piece&7)
#define NRH 16    // hist node ranges
#define NRB 16    // build node ranges
#define HB 1024
#define RCAP 6400 // >= ceil(n/16); n<=102400

// Fused per-copy histograms of dst (cnt8) and src (deg8). Block b: c=b&7, r=b>>3.
// Exclusive owner of cnt8[c][range r] and deg8[c][range r] -> plain-store flush.
__global__ __launch_bounds__(HB) void k_hist_fused(const int* __restrict__ src,
                                                   const int* __restrict__ dst,
                                                   int* __restrict__ deg8,
                                                   int* __restrict__ cnt8, int n, int E) {
    __shared__ int hcnt[RCAP];
    __shared__ int hdeg[RCAP];
    int b = blockIdx.x, c = b & 7, r = b >> 3;
    int t = threadIdx.x;
    const int R = (n + NRH - 1) / NRH;
    int lo = r * R, hi = min(lo + R, n), len = hi - lo;
    for (int q = t; q < len; q += HB) { hcnt[q] = 0; hdeg[q] = 0; }
    __syncthreads();
    int P = (E + 255) >> 8;
    int sub = t >> 8, lane = t & 255;
    for (int m = 0;; ++m) {
        int p = c + 8 * (4 * m + sub);
        if (p >= P) break;
        int e = (p << 8) + lane;
        if (e < E) {
            int d = dst[e];
            if (d >= lo && d < hi) atomicAdd(&hcnt[d - lo], 1);
            int s = src[e];
            if (s >= lo && s < hi) atomicAdd(&hdeg[s - lo], 1);
        }
    }
    __syncthreads();
    int base = c * n + lo;
    for (int q = t; q < len; q += HB) {
        cnt8[base + q] = hcnt[q];
        deg8[base + q] = hdeg[q];
    }
}

// dinv = rsqrt(deg); u = dinv*x; w = -dinv^2; cnt[i] = sum_c cnt8[c][i]
__global__ void k_dinv2(const int* __restrict__ deg8, const int* __restrict__ cnt8,
                        const float* __restrict__ x, float* __restrict__ dinv,
                        float* __restrict__ u, float* __restrict__ w,
                        int* __restrict__ cnt, int n) {
    int i = blockIdx.x * BS + threadIdx.x;
    if (i < n) {
        int d = 0, ci = 0;
        #pragma unroll
        for (int c = 0; c < NC; ++c) { d += deg8[c * n + i]; ci += cnt8[c * n + i]; }
        float df = (float)d;
        float dv = (d > 0) ? rsqrtf(fmaxf(df, 1.0f)) : 0.0f;
        dinv[i] = dv;
        u[i] = dv * x[i];
        w[i] = -dv * dv;
        cnt[i] = ci;
    }
}

// --- scan 1: exclusive scan of flat cnt8 (copy-major, L=8n) -> cur8 = arena offsets ---
__global__ void k_scanA_lin(const int* __restrict__ in, int* __restrict__ outp,
                            int* __restrict__ part, int L) {
    __shared__ int sh[BS];
    int tid = threadIdx.x;
    int base = blockIdx.x * 2048 + tid * 8;
    int v[8];
    int s = 0;
    #pragma unroll
    for (int k = 0; k < 8; ++k) {
        int t = base + k;
        v[k] = (t < L) ? in[t] : 0;
        s += v[k];
    }
    sh[tid] = s; __syncthreads();
    int acc = s;
    for (int d = 1; d < BS; d <<= 1) {
        int add = (tid >= d) ? sh[tid - d] : 0;
        __syncthreads();
        acc += add; sh[tid] = acc;
        __syncthreads();
    }
    int run = acc - s;
    #pragma unroll
    for (int k = 0; k < 8; ++k) {
        int t = base + k;
        if (t < L) outp[t] = run;
        run += v[k];
    }
    if (tid == BS - 1) part[blockIdx.x] = acc;
}

__global__ void k_scanB(int* __restrict__ part, int nb) {  // nb <= 512
    __shared__ int sh[512];
    int t = threadIdx.x;
    int v = (t < nb) ? part[t] : 0;
    sh[t] = v; __syncthreads();
    int acc = v;
    for (int d = 1; d < 512; d <<= 1) {
        int add = (t >= d) ? sh[t - d] : 0;
        __syncthreads();
        acc += add; sh[t] = acc;
        __syncthreads();
    }
    if (t < nb) part[t] = acc - v;  // exclusive
}

__global__ void k_scanC_lin(int* __restrict__ outp, const int* __restrict__ part, int L) {
    int t = blockIdx.x * BS + threadIdx.x;
    if (t < L) outp[t] += part[t >> 11];
}

// --- scan 2: exclusive scan of node totals cnt -> rowptr ---
__global__ void k_scan2A(const int* __restrict__ cnt, int* __restrict__ rowptr,
                         int* __restrict__ part, int n) {
    __shared__ int sh[BS];
    int t = threadIdx.x, i = blockIdx.x * BS + t;
    int v = (i < n) ? cnt[i] : 0;
    sh[t] = v; __syncthreads();
    int acc = v;
    for (int d = 1; d < BS; d <<= 1) {
        int add = (t >= d) ? sh[t - d] : 0;
        __syncthreads();
        acc += add; sh[t] = acc;
        __syncthreads();
    }
    if (i < n) rowptr[i] = acc - v;
    if (t == BS - 1) part[blockIdx.x] = acc;
}

__global__ void k_scan2C(int* __restrict__ rowptr, const int* __restrict__ part, int n, int E) {
    int i = blockIdx.x * BS + threadIdx.x;
    if (i < n) rowptr[i] += part[i >> 8];
    if (i == n) rowptr[n] = E;
}

// Arena fill with LDS cursors. Block b: c=b&7, r=b>>3 (NRB ranges).
// Exclusive owner of (copy c, range r) -> cursors live in LDS, arena region dense.
__global__ __launch_bounds__(HB) void k_build3(const int* __restrict__ src,
                                               const int* __restrict__ dst,
                                               const int* __restrict__ cur8,
                                               int* __restrict__ arena, int n, int E) {
    __shared__ int lcur[RCAP];
    int b = blockIdx.x, c = b & 7, r = b >> 3;
    int t = threadIdx.x;
    const int R = (n + NRB - 1) / NRB;
    int lo = r * R, hi = min(lo + R, n), len = hi - lo;
    int base = c * n + lo;
    for (int q = t; q < len; q += HB) lcur[q] = cur8[base + q];
    __syncthreads();
    int P = (E + 255) >> 8;
    int sub = t >> 8, lane = t & 255;
    for (int m = 0;; ++m) {
        int p = c + 8 * (4 * m + sub);
        if (p >= P) break;
        int e = (p << 8) + lane;
        if (e < E) {
            int d = dst[e];
            if (d >= lo && d < hi) {
                int pos = atomicAdd(&lcur[d - lo], 1);
                arena[pos] = src[e];
            }
        }
    }
}

// merge 8 per-copy fragments of each row into packed colv. 8 lanes per node.
// start = cur8 (scan result, untouched by k_build3), len = cnt8.
__global__ void k_merge(const int* __restrict__ arena, const int* __restrict__ cur8,
                        const int* __restrict__ cnt8, const int* __restrict__ rowptr,
                        int* __restrict__ colv, int n) {
    int t = blockIdx.x * BS + threadIdx.x;
    int i = t >> 3, c = t & 7;
    if (i >= n) return;
    int len = cnt8[c * n + i];
    int start = cur8[c * n + i];
    int pre = len;
    #pragma unroll
    for (int d = 1; d < 8; d <<= 1) {
        int o = __shfl_up(pre, d, 8);
        if ((threadIdx.x & 7) >= d) pre += o;
    }
    pre -= len;
    int p = rowptr[i] + pre;
    for (int j = start; j < start + len; ++j) colv[p++] = arena[j];
}

// scalar gather-sum with 4-deep load pipelining
__global__ void k_prop_s(const int* __restrict__ rowptr, const int* __restrict__ colv,
                         const float* __restrict__ in, float* __restrict__ g,
                         float* __restrict__ vout, const float* __restrict__ w, int n) {
    int i = blockIdx.x * BS + threadIdx.x;
    if (i >= n) return;
    int b = rowptr[i], e = rowptr[i + 1];
    float s = 0.0f;
    int j = b;
    for (; j + 4 <= e; j += 4) {
        int s0 = colv[j], s1 = colv[j + 1], s2 = colv[j + 2], s3 = colv[j + 3];
        float a0 = in[s0], a1 = in[s1], a2 = in[s2], a3 = in[s3];
        s += (a0 + a1) + (a2 + a3);
    }
    for (; j < e; ++j) s += in[colv[j]];
    g[i] = s;
    if (vout) vout[i] = w[i] * s;
}

// 32-dim gather-sum: 4 lanes/node, 2 float4/lane, 4 edges => 8 loads in flight.
__global__ void k_prop_v(const int* __restrict__ rowptr, const int* __restrict__ colv,
                         const float* __restrict__ in, float* __restrict__ out,
                         const float* __restrict__ sc, int n) {
    int t = blockIdx.x * BS + threadIdx.x;
    int node = t >> 2;
    if (node >= n) return;
    int ln8 = (t & 3) << 3;
    int b = rowptr[node], e = rowptr[node + 1];
    float4 accA = make_float4(0.f, 0.f, 0.f, 0.f);
    float4 accB = make_float4(0.f, 0.f, 0.f, 0.f);
    int j = b;
    for (; j + 4 <= e; j += 4) {
        int sx[4];
        #pragma unroll
        for (int q = 0; q < 4; ++q) sx[q] = colv[j + q];
        float4 va[4], vb[4];
        #pragma unroll
        for (int q = 0; q < 4; ++q) {
            const float* p = in + sx[q] * 32 + ln8;
            va[q] = *reinterpret_cast<const float4*>(p);
            vb[q] = *reinterpret_cast<const float4*>(p + 4);
        }
        float mm[4];
        #pragma unroll
        for (int q = 0; q < 4; ++q) mm[q] = sc ? sc[sx[q]] : 1.0f;
        #pragma unroll
        for (int q = 0; q < 4; ++q) {
            accA.x += mm[q] * va[q].x; accA.y += mm[q] * va[q].y;
            accA.z += mm[q] * va[q].z; accA.w += mm[q] * va[q].w;
            accB.x += mm[q] * vb[q].x; accB.y += mm[q] * vb[q].y;
            accB.z += mm[q] * vb[q].z; accB.w += mm[q] * vb[q].w;
        }
    }
    for (; j < e; ++j) {
        int s = colv[j];
        float m = sc ? sc[s] : 1.0f;
        const float* p = in + s * 32 + ln8;
        float4 va = *reinterpret_cast<const float4*>(p);
        float4 vb = *reinterpret_cast<const float4*>(p + 4);
        accA.x += m * va.x; accA.y += m * va.y; accA.z += m * va.z; accA.w += m * va.w;
        accB.x += m * vb.x; accB.y += m * vb.y; accB.z += m * vb.z; accB.w += m * vb.w;
    }
    float* o = out + node * 32 + ln8;
    *reinterpret_cast<float4*>(o) = accA;
    *reinterpret_cast<float4*>(o + 4) = accB;
}

// layer1: Tx1 = -dinv*g1; Tx2 = -2*dinv*g2 - x; h = relu(x*W1[0]+Tx1*W1[1]+Tx2*W1[2]+b1); hs = dinv*h
__global__ void k_layer1(const float* __restrict__ x, const float* __restrict__ g1,
                         const float* __restrict__ g2, const float* __restrict__ dinv,
                         const float* __restrict__ W1, const float* __restrict__ b1,
                         float* __restrict__ h, float* __restrict__ hs, int n) {
    int idx = blockIdx.x * BS + threadIdx.x;
    if (idx < n * 32) {
        int i = idx >> 5, f = idx & 31;
        float x0 = x[i], dv = dinv[i];
        float t1 = -dv * g1[i];
        float t2 = -2.0f * dv * g2[i] - x0;
        float v = x0 * W1[f] + t1 * W1[32 + f] + t2 * W1[64 + f] + b1[f];
        v = fmaxf(v, 0.0f);
        h[idx] = v;
        hs[idx] = dv * v;
    }
}

// layer2+fc: s1 = -dinv*gA; s2 = -2*dinv*gB - h; h2 = relu(h@W2[0]+s1@W2[1]+s2@W2[2]+b2); out = h2@Wfc+bfc
__global__ void k_layer2_fc(const float* __restrict__ h, const float* __restrict__ gA,
                            const float* __restrict__ gB, const float* __restrict__ dinv,
                            const float* __restrict__ W2, const float* __restrict__ b2,
                            const float* __restrict__ Wfc, const float* __restrict__ bfc,
                            float* __restrict__ out, int n) {
    __shared__ float W2s[3 * 32 * 32];
    int tid = threadIdx.x;
    for (int j = tid; j < 3 * 32 * 32; j += BS) W2s[j] = W2[j];
    __syncthreads();
    int f = tid & 31;
    int i = blockIdx.x * 8 + (tid >> 5);
    float acc = 0.0f;
    if (i < n) {
        float dv = dinv[i];
        acc = b2[f];
        const float* hr = h  + (size_t)i * 32;
        const float* ga = gA + (size_t)i * 32;
        const float* gb = gB + (size_t)i * 32;
        #pragma unroll
        for (int k = 0; k < 32; ++k) {
            float hk  = hr[k];
            float s1k = -dv * ga[k];
            float s2k = -2.0f * dv * gb[k] - hk;
            acc += hk * W2s[k * 32 + f] + s1k * W2s[1024 + k * 32 + f] + s2k * W2s[2048 + k * 32 + f];
        }
        acc = fmaxf(acc, 0.0f) * Wfc[f];
    }
    #pragma unroll
    for (int m = 16; m >= 1; m >>= 1) acc += __shfl_xor(acc, m, 32);
    if (i < n && f == 0) out[i] = acc + bfc[0];
}

extern "C" void kernel_launch(void* const* d_in, const int* in_sizes, int n_in,
                              void* d_out, int out_size, void* d_ws, size_t ws_size,
                              hipStream_t stream) {
    const float* x   = (const float*)d_in[0];
    const int*   ei  = (const int*)d_in[1];
    const float* W1  = (const float*)d_in[2];
    const float* b1  = (const float*)d_in[3];
    const float* W2  = (const float*)d_in[4];
    const float* b2  = (const float*)d_in[5];
    const float* Wfc = (const float*)d_in[6];
    const float* bfc = (const float*)d_in[7];
    float* out = (float*)d_out;

    const int n = in_sizes[0];
    const int E = in_sizes[1] / 2;
    const int* src = ei;
    const int* dst = ei + E;

    // workspace layout (4B words); everything fully written before read -> no memset
    int*   cnt8   = (int*)d_ws;                  // 8n
    int*   deg8   = cnt8 + (size_t)NC * n;       // 8n
    int*   cur8   = deg8 + (size_t)NC * n;       // 8n
    int*   cnt    = cur8 + (size_t)NC * n;       // n
    int*   rowptr = cnt + n;                     // n+4
    int*   part   = rowptr + n + 4;              // 512
    float* dinv   = (float*)(part + 512);        // n
    float* u      = dinv + n;                    // n
    float* w      = u + n;                       // n
    float* g1     = w + n;                       // n
    float* v1     = g1 + n;                      // n
    float* g2     = v1 + n;                      // n
    int*   colv   = (int*)(g2 + n);              // E
    float* h      = (float*)(colv + E);          // 32n
    float* hs     = h + (size_t)32 * n;          // 32n; reused as gB
    float* gA     = hs + (size_t)32 * n;         // 32n
    float* gB     = hs;                          // alias
    int*   arena  = (int*)h;                     // E ints, overlaps h (dead until k_layer1)

    const int NB  = (n + BS - 1) / BS;
    const int L   = NC * n;
    const int NBA = (L + 2047) / 2048;           // <=512

    k_hist_fused<<<NC * NRH, HB, 0, stream>>>(src, dst, deg8, cnt8, n, E);
    k_dinv2<<<NB, BS, 0, stream>>>(deg8, cnt8, x, dinv, u, w, cnt, n);
    // scan 1: flat cnt8 -> cur8 (arena offsets; copy-major -> dense per-(c,r) regions)
    k_scanA_lin<<<NBA, BS, 0, stream>>>(cnt8, cur8, part, L);
    k_scanB<<<1, 512, 0, stream>>>(part, NBA);
    k_scanC_lin<<<(L + BS - 1) / BS, BS, 0, stream>>>(cur8, part, L);
    // scan 2: cnt -> rowptr (packed row starts)
    k_scan2A<<<NB, BS, 0, stream>>>(cnt, rowptr, part, n);
    k_scanB<<<1, 512, 0, stream>>>(part, NB);
    k_scan2C<<<NB + 1, BS, 0, stream>>>(rowptr, part, n, E);
    // arena fill (LDS cursors) + merge to packed colv
    k_build3<<<NC * NRB, HB, 0, stream>>>(src, dst, cur8, arena, n, E);
    k_merge<<<(n * 8 + BS - 1) / BS, BS, 0, stream>>>(arena, cur8, cnt8, rowptr, colv, n);

    // layer 1 (scalar)
    k_prop_s<<<NB, BS, 0, stream>>>(rowptr, colv, u, g1, v1, w, n);
    k_prop_s<<<NB, BS, 0, stream>>>(rowptr, colv, v1, g2, nullptr, nullptr, n);
    k_layer1<<<(n * 32 + BS - 1) / BS, BS, 0, stream>>>(x, g1, g2, dinv, W1, b1, h, hs, n);

    // layer 2 (32-dim)
    k_prop_v<<<(n * 4 + BS - 1) / BS, BS, 0, stream>>>(rowptr, colv, hs, gA, nullptr, n);
    k_prop_v<<<(n * 4 + BS - 1) / BS, BS, 0, stream>>>(rowptr, colv, gA, gB, w, n);
    k_layer2_fc<<<(n + 7) / 8, BS, 0, stream>>>(h, gA, gB, dinv, W2, b2, Wfc, bfc, out, n);
}

// Round 10
// 447.794 us; speedup vs baseline: 1.3836x; 1.3836x over previous
//
#include <hip/hip_runtime.h>

// ChebNet K=3. Zero global atomics, zero memsets, no merge pass:
//  - k_hist16: fused per-(copy,range)-exclusive LDS histograms (cnt16 + deg16), plain-store flush
//  - k_frag:   per-row fragment cursors cur16[c][i] = rowptr[i] + prefix_c(cnt16)[i]
//  - k_build16: LDS cursors, writes PACKED colv directly (row-contiguous fragments)
//  - gather-side props (8 lanes/node, 8-deep pipeline)
// copy of edge e = (e>>8) & 15 everywhere (piece = 256 edges).

#define BS 256
#define NC 16     // copies
#define NRH 16    // hist node ranges
#define NRB 16    // build node ranges
#define HB 1024
#define RCAP 6400 // >= ceil(n/16); n <= 102400

// Fused histograms: block b -> (c = b&15, r = b>>4); exclusive owner of (c, range r).
__global__ __launch_bounds__(HB) void k_hist16(const int* __restrict__ src,
                                               const int* __restrict__ dst,
                                               int* __restrict__ deg16,
                                               int* __restrict__ cnt16, int n, int E) {
    __shared__ int hcnt[RCAP];
    __shared__ int hdeg[RCAP];
    int b = blockIdx.x, c = b & 15, r = b >> 4;
    int t = threadIdx.x;
    const int R = (n + NRH - 1) / NRH;
    int lo = r * R, hi = min(lo + R, n), len = hi - lo;
    for (int q = t; q < len; q += HB) { hcnt[q] = 0; hdeg[q] = 0; }
    __syncthreads();
    int P = (E + 255) >> 8;
    int sub = t >> 8, lane = t & 255;
    for (int m = 0;; ++m) {
        int p = c + 16 * (4 * m + sub);
        if (p >= P) break;
        int e = (p << 8) + lane;
        if (e < E) {
            int d = dst[e];
            if (d >= lo && d < hi) atomicAdd(&hcnt[d - lo], 1);
            int s = src[e];
            if (s >= lo && s < hi) atomicAdd(&hdeg[s - lo], 1);
        }
    }
    __syncthreads();
    int base = c * n + lo;
    for (int q = t; q < len; q += HB) {
        cnt16[base + q] = hcnt[q];
        deg16[base + q] = hdeg[q];
    }
}

// dinv = rsqrt(deg); u = dinv*x; w = -dinv^2; cnt[i] = sum_c cnt16[c][i]
__global__ void k_dinv16(const int* __restrict__ deg16, const int* __restrict__ cnt16,
                         const float* __restrict__ x, float* __restrict__ dinv,
                         float* __restrict__ u, float* __restrict__ w,
                         int* __restrict__ cnt, int n) {
    int i = blockIdx.x * BS + threadIdx.x;
    if (i < n) {
        int d = 0, ci = 0;
        #pragma unroll
        for (int c = 0; c < NC; ++c) { d += deg16[c * n + i]; ci += cnt16[c * n + i]; }
        float df = (float)d;
        float dv = (d > 0) ? rsqrtf(fmaxf(df, 1.0f)) : 0.0f;
        dinv[i] = dv;
        u[i] = dv * x[i];
        w[i] = -dv * dv;
        cnt[i] = ci;
    }
}

// --- exclusive scan of node totals cnt -> rowptr ---
__global__ void k_scan2A(const int* __restrict__ cnt, int* __restrict__ rowptr,
                         int* __restrict__ part, int n) {
    __shared__ int sh[BS];
    int t = threadIdx.x, i = blockIdx.x * BS + t;
    int v = (i < n) ? cnt[i] : 0;
    sh[t] = v; __syncthreads();
    int acc = v;
    for (int d = 1; d < BS; d <<= 1) {
        int add = (t >= d) ? sh[t - d] : 0;
        __syncthreads();
        acc += add; sh[t] = acc;
        __syncthreads();
    }
    if (i < n) rowptr[i] = acc - v;
    if (t == BS - 1) part[blockIdx.x] = acc;
}

__global__ void k_scanB(int* __restrict__ part, int nb) {  // nb <= 512
    __shared__ int sh[512];
    int t = threadIdx.x;
    int v = (t < nb) ? part[t] : 0;
    sh[t] = v; __syncthreads();
    int acc = v;
    for (int d = 1; d < 512; d <<= 1) {
        int add = (t >= d) ? sh[t - d] : 0;
        __syncthreads();
        acc += add; sh[t] = acc;
        __syncthreads();
    }
    if (t < nb) part[t] = acc - v;  // exclusive
}

__global__ void k_scan2C(int* __restrict__ rowptr, const int* __restrict__ part, int n, int E) {
    int i = blockIdx.x * BS + threadIdx.x;
    if (i < n) rowptr[i] += part[i >> 8];
    if (i == n) rowptr[n] = E;
}

// fragment cursors: cur16[c][i] = rowptr[i] + sum_{c'<c} cnt16[c'][i]
__global__ void k_frag(const int* __restrict__ cnt16, const int* __restrict__ rowptr,
                       int* __restrict__ cur16, int n) {
    int i = blockIdx.x * BS + threadIdx.x;
    if (i < n) {
        int run = rowptr[i];
        #pragma unroll
        for (int c = 0; c < NC; ++c) {
            cur16[c * n + i] = run;
            run += cnt16[c * n + i];
        }
    }
}

// Direct packed-colv fill with LDS cursors. Block b -> (r = b&15, c = b>>4):
// same-range blocks are stride-16 apart => same XCD under %8 round-robin.
__global__ __launch_bounds__(HB) void k_build16(const int* __restrict__ src,
                                                const int* __restrict__ dst,
                                                const int* __restrict__ cur16,
                                                int* __restrict__ colv, int n, int E) {
    __shared__ int lcur[RCAP];
    int b = blockIdx.x, r = b & 15, c = b >> 4;
    int t = threadIdx.x;
    const int R = (n + NRB - 1) / NRB;
    int lo = r * R, hi = min(lo + R, n), len = hi - lo;
    int base = c * n + lo;
    for (int q = t; q < len; q += HB) lcur[q] = cur16[base + q];
    __syncthreads();
    int P = (E + 255) >> 8;
    int sub = t >> 8, lane = t & 255;
    for (int m = 0;; ++m) {
        int p = c + 16 * (4 * m + sub);
        if (p >= P) break;
        int e = (p << 8) + lane;
        if (e < E) {
            int d = dst[e];
            if (d >= lo && d < hi) {
                int pos = atomicAdd(&lcur[d - lo], 1);
                colv[pos] = src[e];
            }
        }
    }
}

// scalar gather-sum with 4-deep load pipelining
__global__ void k_prop_s(const int* __restrict__ rowptr, const int* __restrict__ colv,
                         const float* __restrict__ in, float* __restrict__ g,
                         float* __restrict__ vout, const float* __restrict__ w, int n) {
    int i = blockIdx.x * BS + threadIdx.x;
    if (i >= n) return;
    int b = rowptr[i], e = rowptr[i + 1];
    float s = 0.0f;
    int j = b;
    for (; j + 4 <= e; j += 4) {
        int s0 = colv[j], s1 = colv[j + 1], s2 = colv[j + 2], s3 = colv[j + 3];
        float a0 = in[s0], a1 = in[s1], a2 = in[s2], a3 = in[s3];
        s += (a0 + a1) + (a2 + a3);
    }
    for (; j < e; ++j) s += in[colv[j]];
    g[i] = s;
    if (vout) vout[i] = w[i] * s;
}

// 32-dim gather-sum: 8 lanes/node, float4/lane, 8 gathers in flight.
__global__ void k_prop_v(const int* __restrict__ rowptr, const int* __restrict__ colv,
                         const float* __restrict__ in, float* __restrict__ out,
                         const float* __restrict__ sc, int n) {
    int t = blockIdx.x * BS + threadIdx.x;
    int node = t >> 3;
    if (node >= n) return;
    int ln4 = (t & 7) << 2;
    int b = rowptr[node], e = rowptr[node + 1];
    float4 acc = make_float4(0.f, 0.f, 0.f, 0.f);
    int j = b;
    for (; j + 8 <= e; j += 8) {
        int sx[8];
        #pragma unroll
        for (int q = 0; q < 8; ++q) sx[q] = colv[j + q];
        float4 vv[8];
        #pragma unroll
        for (int q = 0; q < 8; ++q) vv[q] = *reinterpret_cast<const float4*>(in + sx[q] * 32 + ln4);
        float mm[8];
        #pragma unroll
        for (int q = 0; q < 8; ++q) mm[q] = sc ? sc[sx[q]] : 1.0f;
        #pragma unroll
        for (int q = 0; q < 8; ++q) {
            acc.x += mm[q] * vv[q].x; acc.y += mm[q] * vv[q].y;
            acc.z += mm[q] * vv[q].z; acc.w += mm[q] * vv[q].w;
        }
    }
    for (; j < e; ++j) {
        int s = colv[j];
        float m = sc ? sc[s] : 1.0f;
        float4 v = *reinterpret_cast<const float4*>(in + s * 32 + ln4);
        acc.x += m * v.x; acc.y += m * v.y; acc.z += m * v.z; acc.w += m * v.w;
    }
    *reinterpret_cast<float4*>(out + node * 32 + ln4) = acc;
}

// layer1: Tx1 = -dinv*g1; Tx2 = -2*dinv*g2 - x; h = relu(x*W1[0]+Tx1*W1[1]+Tx2*W1[2]+b1); hs = dinv*h
__global__ void k_layer1(const float* __restrict__ x, const float* __restrict__ g1,
                         const float* __restrict__ g2, const float* __restrict__ dinv,
                         const float* __restrict__ W1, const float* __restrict__ b1,
                         float* __restrict__ h, float* __restrict__ hs, int n) {
    int idx = blockIdx.x * BS + threadIdx.x;
    if (idx < n * 32) {
        int i = idx >> 5, f = idx & 31;
        float x0 = x[i], dv = dinv[i];
        float t1 = -dv * g1[i];
        float t2 = -2.0f * dv * g2[i] - x0;
        float v = x0 * W1[f] + t1 * W1[32 + f] + t2 * W1[64 + f] + b1[f];
        v = fmaxf(v, 0.0f);
        h[idx] = v;
        hs[idx] = dv * v;
    }
}

// layer2+fc: s1 = -dinv*gA; s2 = -2*dinv*gB - h; h2 = relu(h@W2[0]+s1@W2[1]+s2@W2[2]+b2); out = h2@Wfc+bfc
__global__ void k_layer2_fc(const float* __restrict__ h, const float* __restrict__ gA,
                            const float* __restrict__ gB, const float* __restrict__ dinv,
                            const float* __restrict__ W2, const float* __restrict__ b2,
                            const float* __restrict__ Wfc, const float* __restrict__ bfc,
                            float* __restrict__ out, int n) {
    __shared__ float W2s[3 * 32 * 32];
    int tid = threadIdx.x;
    for (int j = tid; j < 3 * 32 * 32; j += BS) W2s[j] = W2[j];
    __syncthreads();
    int f = tid & 31;
    int i = blockIdx.x * 8 + (tid >> 5);
    float acc = 0.0f;
    if (i < n) {
        float dv = dinv[i];
        acc = b2[f];
        const float* hr = h  + (size_t)i * 32;
        const float* ga = gA + (size_t)i * 32;
        const float* gb = gB + (size_t)i * 32;
        #pragma unroll
        for (int k = 0; k < 32; ++k) {
            float hk  = hr[k];
            float s1k = -dv * ga[k];
            float s2k = -2.0f * dv * gb[k] - hk;
            acc += hk * W2s[k * 32 + f] + s1k * W2s[1024 + k * 32 + f] + s2k * W2s[2048 + k * 32 + f];
        }
        acc = fmaxf(acc, 0.0f) * Wfc[f];
    }
    #pragma unroll
    for (int m = 16; m >= 1; m >>= 1) acc += __shfl_xor(acc, m, 32);
    if (i < n && f == 0) out[i] = acc + bfc[0];
}

extern "C" void kernel_launch(void* const* d_in, const int* in_sizes, int n_in,
                              void* d_out, int out_size, void* d_ws, size_t ws_size,
                              hipStream_t stream) {
    const float* x   = (const float*)d_in[0];
    const int*   ei  = (const int*)d_in[1];
    const float* W1  = (const float*)d_in[2];
    const float* b1  = (const float*)d_in[3];
    const float* W2  = (const float*)d_in[4];
    const float* b2  = (const float*)d_in[5];
    const float* Wfc = (const float*)d_in[6];
    const float* bfc = (const float*)d_in[7];
    float* out = (float*)d_out;

    const int n = in_sizes[0];
    const int E = in_sizes[1] / 2;
    const int* src = ei;
    const int* dst = ei + E;

    // workspace layout (4B words). 16n int arrays are ALIASED into the big float
    // buffers (dead until the layer kernels): cnt16->h, cur16->hs, deg16->gA.
    int*   cnt    = (int*)d_ws;                  // n
    int*   rowptr = cnt + n;                     // n+4
    int*   part   = rowptr + n + 4;              // 512
    float* dinv   = (float*)(part + 512);        // n
    float* u      = dinv + n;                    // n
    float* w      = u + n;                       // n
    float* g1     = w + n;                       // n
    float* v1     = g1 + n;                      // n
    float* g2     = v1 + n;                      // n
    int*   colv   = (int*)(g2 + n);              // E
    float* h      = (float*)(colv + E);          // 32n
    float* hs     = h + (size_t)32 * n;          // 32n
    float* gA     = hs + (size_t)32 * n;         // 32n
    float* gB     = hs;                          // alias (hs consumed by prop_v1 before gB write)
    int*   cnt16  = (int*)h;                     // 16n, dead before k_layer1 writes h
    int*   cur16  = (int*)hs;                    // 16n, dead before k_layer1 writes hs
    int*   deg16  = (int*)gA;                    // 16n, dead before k_prop_v writes gA

    const int NB = (n + BS - 1) / BS;

    k_hist16<<<NC * NRH, HB, 0, stream>>>(src, dst, deg16, cnt16, n, E);
    k_dinv16<<<NB, BS, 0, stream>>>(deg16, cnt16, x, dinv, u, w, cnt, n);
    k_scan2A<<<NB, BS, 0, stream>>>(cnt, rowptr, part, n);
    k_scanB<<<1, 512, 0, stream>>>(part, NB);
    k_scan2C<<<NB + 1, BS, 0, stream>>>(rowptr, part, n, E);
    k_frag<<<NB, BS, 0, stream>>>(cnt16, rowptr, cur16, n);
    k_build16<<<NC * NRB, HB, 0, stream>>>(src, dst, cur16, colv, n, E);

    // layer 1 (scalar)
    k_prop_s<<<NB, BS, 0, stream>>>(rowptr, colv, u, g1, v1, w, n);
    k_prop_s<<<NB, BS, 0, stream>>>(rowptr, colv, v1, g2, nullptr, nullptr, n);
    k_layer1<<<(n * 32 + BS - 1) / BS, BS, 0, stream>>>(x, g1, g2, dinv, W1, b1, h, hs, n);

    // layer 2 (32-dim)
    k_prop_v<<<(n * 8 + BS - 1) / BS, BS, 0, stream>>>(rowptr, colv, hs, gA, nullptr, n);
    k_prop_v<<<(n * 8 + BS - 1) / BS, BS, 0, stream>>>(rowptr, colv, gA, gB, w, n);
    k_layer2_fc<<<(n + 7) / 8, BS, 0, stream>>>(h, gA, gB, dinv, W2, b2, Wfc, bfc, out, n);
}

// Round 11
// 356.774 us; speedup vs baseline: 1.7365x; 1.2551x over previous
//
#include <hip/hip_runtime.h>

// ChebNet K=3. Zero global atomics, zero memsets, no merge pass.
//  - copies = NC contiguous edge chunks (copy of edge e = e/ce) -> int4 vector loads
//  - k_hist32: fused per-(copy,range)-exclusive LDS histograms, plain-store flush
//    grid b = r*NC+c -> XCD=c%8: copy chunk L2-resident per XCD (16x reuse)
//  - k_frag: cur32[c][i] = rowptr[i] + prefix_c(cnt32[.][i])
//  - k_build32: LDS cursors, packed colv direct; grid b = c*NRB+r -> XCD=r%8:
//    single-XCD writer set per colv range
//  - gather-side props (8 lanes/node, 8-deep pipeline)

#define BS 256
#define NC 32     // edge-chunk copies
#define NRH 16    // hist node ranges
#define NRB 16    // build node ranges
#define HB 1024
#define RCAP 6250 // ceil(n/16), n <= 100000

__global__ __launch_bounds__(HB) void k_hist32(const int* __restrict__ src,
                                               const int* __restrict__ dst,
                                               int* __restrict__ deg32,
                                               int* __restrict__ cnt32,
                                               int n, int E, int ce) {
    __shared__ int hcnt[RCAP];
    __shared__ int hdeg[RCAP];
    int b = blockIdx.x, c = b & (NC - 1), r = b >> 5;
    int t = threadIdx.x;
    const int R = (n + NRH - 1) / NRH;
    int lo = r * R, hi = min(lo + R, n), len = hi - lo;
    for (int q = t; q < len; q += HB) { hcnt[q] = 0; hdeg[q] = 0; }
    __syncthreads();
    int e0 = c * ce, e1 = min(e0 + ce, E);
    if (e0 < e1) {
        const int4* d4 = reinterpret_cast<const int4*>(dst + e0);
        const int4* s4 = reinterpret_cast<const int4*>(src + e0);
        int L4 = (e1 - e0) >> 2;
        for (int m = 0; m * 4 * HB < L4; ++m) {
            int4 dv[4], sv[4];
            bool ok[4];
            #pragma unroll
            for (int q = 0; q < 4; ++q) {
                int idx = t + (m * 4 + q) * HB;
                ok[q] = idx < L4;
                if (ok[q]) { dv[q] = d4[idx]; sv[q] = s4[idx]; }
            }
            #pragma unroll
            for (int q = 0; q < 4; ++q) if (ok[q]) {
                int d;
                d = dv[q].x; if (d >= lo && d < hi) atomicAdd(&hcnt[d - lo], 1);
                d = dv[q].y; if (d >= lo && d < hi) atomicAdd(&hcnt[d - lo], 1);
                d = dv[q].z; if (d >= lo && d < hi) atomicAdd(&hcnt[d - lo], 1);
                d = dv[q].w; if (d >= lo && d < hi) atomicAdd(&hcnt[d - lo], 1);
                d = sv[q].x; if (d >= lo && d < hi) atomicAdd(&hdeg[d - lo], 1);
                d = sv[q].y; if (d >= lo && d < hi) atomicAdd(&hdeg[d - lo], 1);
                d = sv[q].z; if (d >= lo && d < hi) atomicAdd(&hdeg[d - lo], 1);
                d = sv[q].w; if (d >= lo && d < hi) atomicAdd(&hdeg[d - lo], 1);
            }
        }
        for (int e = e0 + ((e1 - e0) & ~3) + t; e < e1; e += HB) {  // tail (ce%4==0 -> empty)
            int d = dst[e];
            if (d >= lo && d < hi) atomicAdd(&hcnt[d - lo], 1);
            int s = src[e];
            if (s >= lo && s < hi) atomicAdd(&hdeg[s - lo], 1);
        }
    }
    __syncthreads();
    int base = c * n + lo;
    for (int q = t; q < len; q += HB) {
        cnt32[base + q] = hcnt[q];
        deg32[base + q] = hdeg[q];
    }
}

// dinv = rsqrt(deg); u = dinv*x; w = -dinv^2; cnt[i] = sum_c cnt32[c][i]
__global__ void k_dinv32(const int* __restrict__ deg32, const int* __restrict__ cnt32,
                         const float* __restrict__ x, float* __restrict__ dinv,
                         float* __restrict__ u, float* __restrict__ w,
                         int* __restrict__ cnt, int n) {
    int i = blockIdx.x * BS + threadIdx.x;
    if (i < n) {
        int d = 0, ci = 0;
        #pragma unroll
        for (int c = 0; c < NC; ++c) { d += deg32[c * n + i]; ci += cnt32[c * n + i]; }
        float df = (float)d;
        float dv = (d > 0) ? rsqrtf(fmaxf(df, 1.0f)) : 0.0f;
        dinv[i] = dv;
        u[i] = dv * x[i];
        w[i] = -dv * dv;
        cnt[i] = ci;
    }
}

// --- exclusive scan of node totals cnt -> rowptr ---
__global__ void k_scan2A(const int* __restrict__ cnt, int* __restrict__ rowptr,
                         int* __restrict__ part, int n) {
    __shared__ int sh[BS];
    int t = threadIdx.x, i = blockIdx.x * BS + t;
    int v = (i < n) ? cnt[i] : 0;
    sh[t] = v; __syncthreads();
    int acc = v;
    for (int d = 1; d < BS; d <<= 1) {
        int add = (t >= d) ? sh[t - d] : 0;
        __syncthreads();
        acc += add; sh[t] = acc;
        __syncthreads();
    }
    if (i < n) rowptr[i] = acc - v;
    if (t == BS - 1) part[blockIdx.x] = acc;
}

__global__ void k_scanB(int* __restrict__ part, int nb) {  // nb <= 512
    __shared__ int sh[512];
    int t = threadIdx.x;
    int v = (t < nb) ? part[t] : 0;
    sh[t] = v; __syncthreads();
    int acc = v;
    for (int d = 1; d < 512; d <<= 1) {
        int add = (t >= d) ? sh[t - d] : 0;
        __syncthreads();
        acc += add; sh[t] = acc;
        __syncthreads();
    }
    if (t < nb) part[t] = acc - v;  // exclusive
}

__global__ void k_scan2C(int* __restrict__ rowptr, const int* __restrict__ part, int n, int E) {
    int i = blockIdx.x * BS + threadIdx.x;
    if (i < n) rowptr[i] += part[i >> 8];
    if (i == n) rowptr[n] = E;
}

// fragment cursors: cur32[c][i] = rowptr[i] + sum_{c'<c} cnt32[c'][i]
__global__ void k_frag(const int* __restrict__ cnt32, const int* __restrict__ rowptr,
                       int* __restrict__ cur32, int n) {
    int i = blockIdx.x * BS + threadIdx.x;
    if (i < n) {
        int run = rowptr[i];
        #pragma unroll
        for (int c = 0; c < NC; ++c) {
            cur32[c * n + i] = run;
            run += cnt32[c * n + i];
        }
    }
}

// Direct packed-colv fill with LDS cursors. Block b -> (r = b&15, c = b>>4).
__global__ __launch_bounds__(HB) void k_build32(const int* __restrict__ src,
                                                const int* __restrict__ dst,
                                                const int* __restrict__ cur32,
                                                int* __restrict__ colv,
                                                int n, int E, int ce) {
    __shared__ int lcur[RCAP];
    int b = blockIdx.x, r = b & (NRB - 1), c = b >> 4;
    int t = threadIdx.x;
    const int R = (n + NRB - 1) / NRB;
    int lo = r * R, hi = min(lo + R, n), len = hi - lo;
    int base = c * n + lo;
    for (int q = t; q < len; q += HB) lcur[q] = cur32[base + q];
    __syncthreads();
    int e0 = c * ce, e1 = min(e0 + ce, E);
    if (e0 < e1) {
        const int4* d4 = reinterpret_cast<const int4*>(dst + e0);
        const int4* s4 = reinterpret_cast<const int4*>(src + e0);
        int L4 = (e1 - e0) >> 2;
        for (int m = 0; m * 4 * HB < L4; ++m) {
            int4 dv[4], sv[4];
            bool ok[4];
            #pragma unroll
            for (int q = 0; q < 4; ++q) {
                int idx = t + (m * 4 + q) * HB;
                ok[q] = idx < L4;
                if (ok[q]) { dv[q] = d4[idx]; sv[q] = s4[idx]; }
            }
            #pragma unroll
            for (int q = 0; q < 4; ++q) if (ok[q]) {
                int d;
                d = dv[q].x; if (d >= lo && d < hi) { int p = atomicAdd(&lcur[d - lo], 1); colv[p] = sv[q].x; }
                d = dv[q].y; if (d >= lo && d < hi) { int p = atomicAdd(&lcur[d - lo], 1); colv[p] = sv[q].y; }
                d = dv[q].z; if (d >= lo && d < hi) { int p = atomicAdd(&lcur[d - lo], 1); colv[p] = sv[q].z; }
                d = dv[q].w; if (d >= lo && d < hi) { int p = atomicAdd(&lcur[d - lo], 1); colv[p] = sv[q].w; }
            }
        }
        for (int e = e0 + ((e1 - e0) & ~3) + t; e < e1; e += HB) {
            int d = dst[e];
            if (d >= lo && d < hi) { int p = atomicAdd(&lcur[d - lo], 1); colv[p] = src[e]; }
        }
    }
}

// scalar gather-sum with 4-deep load pipelining
__global__ void k_prop_s(const int* __restrict__ rowptr, const int* __restrict__ colv,
                         const float* __restrict__ in, float* __restrict__ g,
                         float* __restrict__ vout, const float* __restrict__ w, int n) {
    int i = blockIdx.x * BS + threadIdx.x;
    if (i >= n) return;
    int b = rowptr[i], e = rowptr[i + 1];
    float s = 0.0f;
    int j = b;
    for (; j + 4 <= e; j += 4) {
        int s0 = colv[j], s1 = colv[j + 1], s2 = colv[j + 2], s3 = colv[j + 3];
        float a0 = in[s0], a1 = in[s1], a2 = in[s2], a3 = in[s3];
        s += (a0 + a1) + (a2 + a3);
    }
    for (; j < e; ++j) s += in[colv[j]];
    g[i] = s;
    if (vout) vout[i] = w[i] * s;
}

// 32-dim gather-sum: 8 lanes/node, float4/lane, 8 gathers in flight.
__global__ void k_prop_v(const int* __restrict__ rowptr, const int* __restrict__ colv,
                         const float* __restrict__ in, float* __restrict__ out,
                         const float* __restrict__ sc, int n) {
    int t = blockIdx.x * BS + threadIdx.x;
    int node = t >> 3;
    if (node >= n) return;
    int ln4 = (t & 7) << 2;
    int b = rowptr[node], e = rowptr[node + 1];
    float4 acc = make_float4(0.f, 0.f, 0.f, 0.f);
    int j = b;
    for (; j + 8 <= e; j += 8) {
        int sx[8];
        #pragma unroll
        for (int q = 0; q < 8; ++q) sx[q] = colv[j + q];
        float4 vv[8];
        #pragma unroll
        for (int q = 0; q < 8; ++q) vv[q] = *reinterpret_cast<const float4*>(in + sx[q] * 32 + ln4);
        float mm[8];
        #pragma unroll
        for (int q = 0; q < 8; ++q) mm[q] = sc ? sc[sx[q]] : 1.0f;
        #pragma unroll
        for (int q = 0; q < 8; ++q) {
            acc.x += mm[q] * vv[q].x; acc.y += mm[q] * vv[q].y;
            acc.z += mm[q] * vv[q].z; acc.w += mm[q] * vv[q].w;
        }
    }
    for (; j < e; ++j) {
        int s = colv[j];
        float m = sc ? sc[s] : 1.0f;
        float4 v = *reinterpret_cast<const float4*>(in + s * 32 + ln4);
        acc.x += m * v.x; acc.y += m * v.y; acc.z += m * v.z; acc.w += m * v.w;
    }
    *reinterpret_cast<float4*>(out + node * 32 + ln4) = acc;
}

// layer1: Tx1 = -dinv*g1; Tx2 = -2*dinv*g2 - x; h = relu(x*W1[0]+Tx1*W1[1]+Tx2*W1[2]+b1); hs = dinv*h
__global__ void k_layer1(const float* __restrict__ x, const float* __restrict__ g1,
                         const float* __restrict__ g2, const float* __restrict__ dinv,
                         const float* __restrict__ W1, const float* __restrict__ b1,
                         float* __restrict__ h, float* __restrict__ hs, int n) {
    int idx = blockIdx.x * BS + threadIdx.x;
    if (idx < n * 32) {
        int i = idx >> 5, f = idx & 31;
        float x0 = x[i], dv = dinv[i];
        float t1 = -dv * g1[i];
        float t2 = -2.0f * dv * g2[i] - x0;
        float v = x0 * W1[f] + t1 * W1[32 + f] + t2 * W1[64 + f] + b1[f];
        v = fmaxf(v, 0.0f);
        h[idx] = v;
        hs[idx] = dv * v;
    }
}

// layer2+fc
__global__ void k_layer2_fc(const float* __restrict__ h, const float* __restrict__ gA,
                            const float* __restrict__ gB, const float* __restrict__ dinv,
                            const float* __restrict__ W2, const float* __restrict__ b2,
                            const float* __restrict__ Wfc, const float* __restrict__ bfc,
                            float* __restrict__ out, int n) {
    __shared__ float W2s[3 * 32 * 32];
    int tid = threadIdx.x;
    for (int j = tid; j < 3 * 32 * 32; j += BS) W2s[j] = W2[j];
    __syncthreads();
    int f = tid & 31;
    int i = blockIdx.x * 8 + (tid >> 5);
    float acc = 0.0f;
    if (i < n) {
        float dv = dinv[i];
        acc = b2[f];
        const float* hr = h  + (size_t)i * 32;
        const float* ga = gA + (size_t)i * 32;
        const float* gb = gB + (size_t)i * 32;
        #pragma unroll
        for (int k = 0; k < 32; ++k) {
            float hk  = hr[k];
            float s1k = -dv * ga[k];
            float s2k = -2.0f * dv * gb[k] - hk;
            acc += hk * W2s[k * 32 + f] + s1k * W2s[1024 + k * 32 + f] + s2k * W2s[2048 + k * 32 + f];
        }
        acc = fmaxf(acc, 0.0f) * Wfc[f];
    }
    #pragma unroll
    for (int m = 16; m >= 1; m >>= 1) acc += __shfl_xor(acc, m, 32);
    if (i < n && f == 0) out[i] = acc + bfc[0];
}

extern "C" void kernel_launch(void* const* d_in, const int* in_sizes, int n_in,
                              void* d_out, int out_size, void* d_ws, size_t ws_size,
                              hipStream_t stream) {
    const float* x   = (const float*)d_in[0];
    const int*   ei  = (const int*)d_in[1];
    const float* W1  = (const float*)d_in[2];
    const float* b1  = (const float*)d_in[3];
    const float* W2  = (const float*)d_in[4];
    const float* b2  = (const float*)d_in[5];
    const float* Wfc = (const float*)d_in[6];
    const float* bfc = (const float*)d_in[7];
    float* out = (float*)d_out;

    const int n = in_sizes[0];
    const int E = in_sizes[1] / 2;
    const int* src = ei;
    const int* dst = ei + E;
    const int ce = (((E + NC - 1) / NC) + 3) & ~3;  // chunk size, 4-aligned

    // workspace layout (4B words). 32n int arrays ALIASED into float buffers
    // (dead before their float users): cnt32->h, cur32->hs, deg32->gA.
    int*   cnt    = (int*)d_ws;                  // n
    int*   rowptr = cnt + n;                     // n+4
    int*   part   = rowptr + n + 4;              // 512
    float* dinv   = (float*)(part + 512);        // n
    float* u      = dinv + n;                    // n
    float* w      = u + n;                       // n
    float* g1     = w + n;                       // n
    float* v1     = g1 + n;                      // n
    float* g2     = v1 + n;                      // n
    int*   colv   = (int*)(g2 + n);              // E
    float* h      = (float*)(colv + E);          // 32n
    float* hs     = h + (size_t)32 * n;          // 32n
    float* gA     = hs + (size_t)32 * n;         // 32n
    float* gB     = hs;                          // alias (hs consumed by prop_v1 before gB write)
    int*   cnt32  = (int*)h;                     // 32n, dead before k_layer1 writes h
    int*   cur32  = (int*)hs;                    // 32n, dead before k_layer1 writes hs
    int*   deg32  = (int*)gA;                    // 32n, dead before k_prop_v writes gA

    const int NB = (n + BS - 1) / BS;

    k_hist32<<<NC * NRH, HB, 0, stream>>>(src, dst, deg32, cnt32, n, E, ce);
    k_dinv32<<<NB, BS, 0, stream>>>(deg32, cnt32, x, dinv, u, w, cnt, n);
    k_scan2A<<<NB, BS, 0, stream>>>(cnt, rowptr, part, n);
    k_scanB<<<1, 512, 0, stream>>>(part, NB);
    k_scan2C<<<NB + 1, BS, 0, stream>>>(rowptr, part, n, E);
    k_frag<<<NB, BS, 0, stream>>>(cnt32, rowptr, cur32, n);
    k_build32<<<NC * NRB, HB, 0, stream>>>(src, dst, cur32, colv, n, E, ce);

    // layer 1 (scalar)
    k_prop_s<<<NB, BS, 0, stream>>>(rowptr, colv, u, g1, v1, w, n);
    k_prop_s<<<NB, BS, 0, stream>>>(rowptr, colv, v1, g2, nullptr, nullptr, n);
    k_layer1<<<(n * 32 + BS - 1) / BS, BS, 0, stream>>>(x, g1, g2, dinv, W1, b1, h, hs, n);

    // layer 2 (32-dim)
    k_prop_v<<<(n * 8 + BS - 1) / BS, BS, 0, stream>>>(rowptr, colv, hs, gA, nullptr, n);
    k_prop_v<<<(n * 8 + BS - 1) / BS, BS, 0, stream>>>(rowptr, colv, gA, gB, w, n);
    k_layer2_fc<<<(n + 7) / 8, BS, 0, stream>>>(h, gA, gB, dinv, W2, b2, Wfc, bfc, out, n);
}

// Round 14
// 275.428 us; speedup vs baseline: 2.2494x; 1.2953x over previous
//
#include <hip/hip_runtime.h>
#include <hip/hip_fp16.h>

// ChebNet K=3. Zero global atomics. fp16 gather operands (fp32 accum) to halve the
// L2-miss gather traffic; prop_v2 fused with layer2+FC (gB never materialized).
// FIX vs r12: gA16 placed at R2+16n words (hs16 is 16n words, they overlapped).

#define BS 256
#define NC 32     // edge-chunk copies
#define NRH 16    // hist node ranges
#define NRB 16    // build node ranges
#define HB 1024
#define RCAP 6250 // ceil(n/16), n <= 100000

__global__ __launch_bounds__(HB) void k_hist32(const int* __restrict__ src,
                                               const int* __restrict__ dst,
                                               int* __restrict__ deg32,
                                               int* __restrict__ cnt32,
                                               int n, int E, int ce) {
    __shared__ int hcnt[RCAP];
    __shared__ int hdeg[RCAP];
    int b = blockIdx.x, c = b & (NC - 1), r = b >> 5;
    int t = threadIdx.x;
    const int R = (n + NRH - 1) / NRH;
    int lo = r * R, hi = min(lo + R, n), len = hi - lo;
    for (int q = t; q < len; q += HB) { hcnt[q] = 0; hdeg[q] = 0; }
    __syncthreads();
    int e0 = c * ce, e1 = min(e0 + ce, E);
    if (e0 < e1) {
        const int4* d4 = reinterpret_cast<const int4*>(dst + e0);
        const int4* s4 = reinterpret_cast<const int4*>(src + e0);
        int L4 = (e1 - e0) >> 2;
        for (int m = 0; m * 4 * HB < L4; ++m) {
            int4 dv[4], sv[4];
            bool ok[4];
            #pragma unroll
            for (int q = 0; q < 4; ++q) {
                int idx = t + (m * 4 + q) * HB;
                ok[q] = idx < L4;
                if (ok[q]) { dv[q] = d4[idx]; sv[q] = s4[idx]; }
            }
            #pragma unroll
            for (int q = 0; q < 4; ++q) if (ok[q]) {
                int d;
                d = dv[q].x; if (d >= lo && d < hi) atomicAdd(&hcnt[d - lo], 1);
                d = dv[q].y; if (d >= lo && d < hi) atomicAdd(&hcnt[d - lo], 1);
                d = dv[q].z; if (d >= lo && d < hi) atomicAdd(&hcnt[d - lo], 1);
                d = dv[q].w; if (d >= lo && d < hi) atomicAdd(&hcnt[d - lo], 1);
                d = sv[q].x; if (d >= lo && d < hi) atomicAdd(&hdeg[d - lo], 1);
                d = sv[q].y; if (d >= lo && d < hi) atomicAdd(&hdeg[d - lo], 1);
                d = sv[q].z; if (d >= lo && d < hi) atomicAdd(&hdeg[d - lo], 1);
                d = sv[q].w; if (d >= lo && d < hi) atomicAdd(&hdeg[d - lo], 1);
            }
        }
        for (int e = e0 + ((e1 - e0) & ~3) + t; e < e1; e += HB) {
            int d = dst[e];
            if (d >= lo && d < hi) atomicAdd(&hcnt[d - lo], 1);
            int s = src[e];
            if (s >= lo && s < hi) atomicAdd(&hdeg[s - lo], 1);
        }
    }
    __syncthreads();
    int base = c * n + lo;
    for (int q = t; q < len; q += HB) {
        cnt32[base + q] = hcnt[q];
        deg32[base + q] = hdeg[q];
    }
}

__global__ void k_dinv32(const int* __restrict__ deg32, const int* __restrict__ cnt32,
                         const float* __restrict__ x, float* __restrict__ dinv,
                         float* __restrict__ u, float* __restrict__ w,
                         int* __restrict__ cnt, int n) {
    int i = blockIdx.x * BS + threadIdx.x;
    if (i < n) {
        int d = 0, ci = 0;
        #pragma unroll
        for (int c = 0; c < NC; ++c) { d += deg32[c * n + i]; ci += cnt32[c * n + i]; }
        float df = (float)d;
        float dv = (d > 0) ? rsqrtf(fmaxf(df, 1.0f)) : 0.0f;
        dinv[i] = dv;
        u[i] = dv * x[i];
        w[i] = -dv * dv;
        cnt[i] = ci;
    }
}

__global__ void k_scan2A(const int* __restrict__ cnt, int* __restrict__ rowptr,
                         int* __restrict__ part, int n) {
    __shared__ int sh[BS];
    int t = threadIdx.x, i = blockIdx.x * BS + t;
    int v = (i < n) ? cnt[i] : 0;
    sh[t] = v; __syncthreads();
    int acc = v;
    for (int d = 1; d < BS; d <<= 1) {
        int add = (t >= d) ? sh[t - d] : 0;
        __syncthreads();
        acc += add; sh[t] = acc;
        __syncthreads();
    }
    if (i < n) rowptr[i] = acc - v;
    if (t == BS - 1) part[blockIdx.x] = acc;
}

__global__ void k_scanB(int* __restrict__ part, int nb) {
    __shared__ int sh[512];
    int t = threadIdx.x;
    int v = (t < nb) ? part[t] : 0;
    sh[t] = v; __syncthreads();
    int acc = v;
    for (int d = 1; d < 512; d <<= 1) {
        int add = (t >= d) ? sh[t - d] : 0;
        __syncthreads();
        acc += add; sh[t] = acc;
        __syncthreads();
    }
    if (t < nb) part[t] = acc - v;
}

__global__ void k_scan2C(int* __restrict__ rowptr, const int* __restrict__ part, int n, int E) {
    int i = blockIdx.x * BS + threadIdx.x;
    if (i < n) rowptr[i] += part[i >> 8];
    if (i == n) rowptr[n] = E;
}

__global__ void k_frag(const int* __restrict__ cnt32, const int* __restrict__ rowptr,
                       int* __restrict__ cur32, int n) {
    int i = blockIdx.x * BS + threadIdx.x;
    if (i < n) {
        int run = rowptr[i];
        #pragma unroll
        for (int c = 0; c < NC; ++c) {
            cur32[c * n + i] = run;
            run += cnt32[c * n + i];
        }
    }
}

__global__ __launch_bounds__(HB) void k_build32(const int* __restrict__ src,
                                                const int* __restrict__ dst,
                                                const int* __restrict__ cur32,
                                                int* __restrict__ colv,
                                                int n, int E, int ce) {
    __shared__ int lcur[RCAP];
    int b = blockIdx.x, r = b & (NRB - 1), c = b >> 4;
    int t = threadIdx.x;
    const int R = (n + NRB - 1) / NRB;
    int lo = r * R, hi = min(lo + R, n), len = hi - lo;
    int base = c * n + lo;
    for (int q = t; q < len; q += HB) lcur[q] = cur32[base + q];
    __syncthreads();
    int e0 = c * ce, e1 = min(e0 + ce, E);
    if (e0 < e1) {
        const int4* d4 = reinterpret_cast<const int4*>(dst + e0);
        const int4* s4 = reinterpret_cast<const int4*>(src + e0);
        int L4 = (e1 - e0) >> 2;
        for (int m = 0; m * 4 * HB < L4; ++m) {
            int4 dv[4], sv[4];
            bool ok[4];
            #pragma unroll
            for (int q = 0; q < 4; ++q) {
                int idx = t + (m * 4 + q) * HB;
                ok[q] = idx < L4;
                if (ok[q]) { dv[q] = d4[idx]; sv[q] = s4[idx]; }
            }
            #pragma unroll
            for (int q = 0; q < 4; ++q) if (ok[q]) {
                int d;
                d = dv[q].x; if (d >= lo && d < hi) { int p = atomicAdd(&lcur[d - lo], 1); colv[p] = sv[q].x; }
                d = dv[q].y; if (d >= lo && d < hi) { int p = atomicAdd(&lcur[d - lo], 1); colv[p] = sv[q].y; }
                d = dv[q].z; if (d >= lo && d < hi) { int p = atomicAdd(&lcur[d - lo], 1); colv[p] = sv[q].z; }
                d = dv[q].w; if (d >= lo && d < hi) { int p = atomicAdd(&lcur[d - lo], 1); colv[p] = sv[q].w; }
            }
        }
        for (int e = e0 + ((e1 - e0) & ~3) + t; e < e1; e += HB) {
            int d = dst[e];
            if (d >= lo && d < hi) { int p = atomicAdd(&lcur[d - lo], 1); colv[p] = src[e]; }
        }
    }
}

__global__ void k_prop_s(const int* __restrict__ rowptr, const int* __restrict__ colv,
                         const float* __restrict__ in, float* __restrict__ g,
                         float* __restrict__ vout, const float* __restrict__ w, int n) {
    int i = blockIdx.x * BS + threadIdx.x;
    if (i >= n) return;
    int b = rowptr[i], e = rowptr[i + 1];
    float s = 0.0f;
    int j = b;
    for (; j + 4 <= e; j += 4) {
        int s0 = colv[j], s1 = colv[j + 1], s2 = colv[j + 2], s3 = colv[j + 3];
        float a0 = in[s0], a1 = in[s1], a2 = in[s2], a3 = in[s3];
        s += (a0 + a1) + (a2 + a3);
    }
    for (; j < e; ++j) s += in[colv[j]];
    g[i] = s;
    if (vout) vout[i] = w[i] * s;
}

// layer1 -> h (fp32, for FC) and hs16 (fp16, gather operand)
__global__ void k_layer1(const float* __restrict__ x, const float* __restrict__ g1,
                         const float* __restrict__ g2, const float* __restrict__ dinv,
                         const float* __restrict__ W1, const float* __restrict__ b1,
                         float* __restrict__ h, __half* __restrict__ hs16, int n) {
    int idx = blockIdx.x * BS + threadIdx.x;
    if (idx < n * 32) {
        int i = idx >> 5, f = idx & 31;
        float x0 = x[i], dv = dinv[i];
        float t1 = -dv * g1[i];
        float t2 = -2.0f * dv * g2[i] - x0;
        float v = x0 * W1[f] + t1 * W1[32 + f] + t2 * W1[64 + f] + b1[f];
        v = fmaxf(v, 0.0f);
        h[idx] = v;
        hs16[idx] = __float2half_rn(dv * v);
    }
}

// fp16 gather (8 lanes/node, 4 feats/lane, 8 edges in flight): gA fp32 + gA16 fp16
__global__ void k_prop_vh(const int* __restrict__ rowptr, const int* __restrict__ colv,
                          const __half* __restrict__ in16, float* __restrict__ outf,
                          __half* __restrict__ out16, int n) {
    int t = blockIdx.x * BS + threadIdx.x;
    int node = t >> 3;
    if (node >= n) return;
    int ln4 = (t & 7) << 2;
    int b = rowptr[node], e = rowptr[node + 1];
    float4 acc = make_float4(0.f, 0.f, 0.f, 0.f);
    int j = b;
    for (; j + 8 <= e; j += 8) {
        int sx[8];
        #pragma unroll
        for (int q = 0; q < 8; ++q) sx[q] = colv[j + q];
        float2 raw[8];
        #pragma unroll
        for (int q = 0; q < 8; ++q)
            raw[q] = *reinterpret_cast<const float2*>(in16 + (size_t)sx[q] * 32 + ln4);
        #pragma unroll
        for (int q = 0; q < 8; ++q) {
            __half2 p0 = *reinterpret_cast<__half2*>(&raw[q].x);
            __half2 p1 = *reinterpret_cast<__half2*>(&raw[q].y);
            float2 a = __half22float2(p0), c = __half22float2(p1);
            acc.x += a.x; acc.y += a.y; acc.z += c.x; acc.w += c.y;
        }
    }
    for (; j < e; ++j) {
        int s = colv[j];
        float2 raw = *reinterpret_cast<const float2*>(in16 + (size_t)s * 32 + ln4);
        __half2 p0 = *reinterpret_cast<__half2*>(&raw.x);
        __half2 p1 = *reinterpret_cast<__half2*>(&raw.y);
        float2 a = __half22float2(p0), c = __half22float2(p1);
        acc.x += a.x; acc.y += a.y; acc.z += c.x; acc.w += c.y;
    }
    *reinterpret_cast<float4*>(outf + (size_t)node * 32 + ln4) = acc;
    __half2 o0 = __floats2half2_rn(acc.x, acc.y);
    __half2 o1 = __floats2half2_rn(acc.z, acc.w);
    float2 packed;
    *reinterpret_cast<__half2*>(&packed.x) = o0;
    *reinterpret_cast<__half2*>(&packed.y) = o1;
    *reinterpret_cast<float2*>(out16 + (size_t)node * 32 + ln4) = packed;
}

// Fused: gather gB (w[s]*gA16[s]) into regs -> LDS exchange -> layer2 matvec + FC -> out
// 256 threads = 32 nodes x 8 lanes.
__global__ __launch_bounds__(BS) void k_prop_fc(
    const int* __restrict__ rowptr, const int* __restrict__ colv,
    const __half* __restrict__ gA16, const float* __restrict__ h,
    const float* __restrict__ gA, const float* __restrict__ wsc,
    const float* __restrict__ dinv, const float* __restrict__ W2,
    const float* __restrict__ b2, const float* __restrict__ Wfc,
    const float* __restrict__ bfc, float* __restrict__ out, int n) {
    __shared__ float W2s[3 * 32 * 32];
    __shared__ float hx[32][33], gax[32][33], gbx[32][33];
    int tid = threadIdx.x;
    for (int q = tid; q < 3 * 32 * 32; q += BS) W2s[q] = W2[q];
    int nd = tid >> 3, ln = tid & 7, ln4 = ln << 2;
    int i = blockIdx.x * 32 + nd;
    float4 acc = make_float4(0.f, 0.f, 0.f, 0.f);
    if (i < n) {
        int b = rowptr[i], e = rowptr[i + 1];
        int j = b;
        for (; j + 8 <= e; j += 8) {
            int sx[8];
            #pragma unroll
            for (int q = 0; q < 8; ++q) sx[q] = colv[j + q];
            float2 raw[8];
            #pragma unroll
            for (int q = 0; q < 8; ++q)
                raw[q] = *reinterpret_cast<const float2*>(gA16 + (size_t)sx[q] * 32 + ln4);
            float mm[8];
            #pragma unroll
            for (int q = 0; q < 8; ++q) mm[q] = wsc[sx[q]];
            #pragma unroll
            for (int q = 0; q < 8; ++q) {
                __half2 p0 = *reinterpret_cast<__half2*>(&raw[q].x);
                __half2 p1 = *reinterpret_cast<__half2*>(&raw[q].y);
                float2 a = __half22float2(p0), c = __half22float2(p1);
                acc.x += mm[q] * a.x; acc.y += mm[q] * a.y;
                acc.z += mm[q] * c.x; acc.w += mm[q] * c.y;
            }
        }
        for (; j < e; ++j) {
            int s = colv[j];
            float m = wsc[s];
            float2 raw = *reinterpret_cast<const float2*>(gA16 + (size_t)s * 32 + ln4);
            __half2 p0 = *reinterpret_cast<__half2*>(&raw.x);
            __half2 p1 = *reinterpret_cast<__half2*>(&raw.y);
            float2 a = __half22float2(p0), c = __half22float2(p1);
            acc.x += m * a.x; acc.y += m * a.y; acc.z += m * c.x; acc.w += m * c.y;
        }
        float4 hv  = *reinterpret_cast<const float4*>(h  + (size_t)i * 32 + ln4);
        float4 gav = *reinterpret_cast<const float4*>(gA + (size_t)i * 32 + ln4);
        hx[nd][ln4 + 0] = hv.x;  hx[nd][ln4 + 1] = hv.y;
        hx[nd][ln4 + 2] = hv.z;  hx[nd][ln4 + 3] = hv.w;
        gax[nd][ln4 + 0] = gav.x; gax[nd][ln4 + 1] = gav.y;
        gax[nd][ln4 + 2] = gav.z; gax[nd][ln4 + 3] = gav.w;
        gbx[nd][ln4 + 0] = acc.x; gbx[nd][ln4 + 1] = acc.y;
        gbx[nd][ln4 + 2] = acc.z; gbx[nd][ln4 + 3] = acc.w;
    }
    __syncthreads();
    if (i < n) {
        float dv = dinv[i];
        float a0 = b2[ln4 + 0], a1 = b2[ln4 + 1], a2 = b2[ln4 + 2], a3 = b2[ln4 + 3];
        #pragma unroll 8
        for (int k = 0; k < 32; ++k) {
            float hk  = hx[nd][k];
            float s1k = -dv * gax[nd][k];
            float s2k = -2.0f * dv * gbx[nd][k] - hk;
            const float* w0 = W2s + k * 32 + ln4;
            a0 += hk * w0[0] + s1k * w0[1024] + s2k * w0[2048];
            a1 += hk * w0[1] + s1k * w0[1025] + s2k * w0[2049];
            a2 += hk * w0[2] + s1k * w0[1026] + s2k * w0[2050];
            a3 += hk * w0[3] + s1k * w0[1027] + s2k * w0[2051];
        }
        float p = fmaxf(a0, 0.f) * Wfc[ln4 + 0] + fmaxf(a1, 0.f) * Wfc[ln4 + 1]
                + fmaxf(a2, 0.f) * Wfc[ln4 + 2] + fmaxf(a3, 0.f) * Wfc[ln4 + 3];
        #pragma unroll
        for (int m = 4; m >= 1; m >>= 1) p += __shfl_xor(p, m, 8);
        if (ln == 0) out[i] = p + bfc[0];
    }
}

extern "C" void kernel_launch(void* const* d_in, const int* in_sizes, int n_in,
                              void* d_out, int out_size, void* d_ws, size_t ws_size,
                              hipStream_t stream) {
    const float* x   = (const float*)d_in[0];
    const int*   ei  = (const int*)d_in[1];
    const float* W1  = (const float*)d_in[2];
    const float* b1  = (const float*)d_in[3];
    const float* W2  = (const float*)d_in[4];
    const float* b2  = (const float*)d_in[5];
    const float* Wfc = (const float*)d_in[6];
    const float* bfc = (const float*)d_in[7];
    float* out = (float*)d_out;

    const int n = in_sizes[0];
    const int E = in_sizes[1] / 2;
    const int* src = ei;
    const int* dst = ei + E;
    const int ce = (((E + NC - 1) / NC) + 3) & ~3;

    // workspace (4B words). R1=h/cnt32 (32n), R2=[hs16 16n | gA16 16n]/cur32 (32n),
    // R3=gA/deg32 (32n). hs16 = 32n halfs = 16n words; gA16 at word 16n -> disjoint.
    int*   cnt    = (int*)d_ws;                  // n
    int*   rowptr = cnt + n;                     // n+4
    int*   part   = rowptr + n + 4;              // 512
    float* dinv   = (float*)(part + 512);        // n
    float* u      = dinv + n;                    // n
    float* w      = u + n;                       // n
    float* g1     = w + n;                       // n
    float* v1     = g1 + n;                      // n
    float* g2     = v1 + n;                      // n
    int*   colv   = (int*)(g2 + n);              // E
    float* h      = (float*)(colv + E);          // 32n (R1)
    float* R2     = h + (size_t)32 * n;          // 32n
    float* gA     = R2 + (size_t)32 * n;         // 32n (R3)
    __half* hs16  = (__half*)R2;                    // 32n halfs = 16n words
    __half* gA16  = (__half*)(R2 + (size_t)16 * n); // 32n halfs = 16n words
    int*   cnt32  = (int*)h;                     // dead before k_layer1 writes h
    int*   cur32  = (int*)R2;                    // dead before k_layer1 writes hs16
    int*   deg32  = (int*)gA;                    // dead before k_prop_vh writes gA

    const int NB = (n + BS - 1) / BS;

    k_hist32<<<NC * NRH, HB, 0, stream>>>(src, dst, deg32, cnt32, n, E, ce);
    k_dinv32<<<NB, BS, 0, stream>>>(deg32, cnt32, x, dinv, u, w, cnt, n);
    k_scan2A<<<NB, BS, 0, stream>>>(cnt, rowptr, part, n);
    k_scanB<<<1, 512, 0, stream>>>(part, NB);
    k_scan2C<<<NB + 1, BS, 0, stream>>>(rowptr, part, n, E);
    k_frag<<<NB, BS, 0, stream>>>(cnt32, rowptr, cur32, n);
    k_build32<<<NC * NRB, HB, 0, stream>>>(src, dst, cur32, colv, n, E, ce);

    // layer 1 (scalar)
    k_prop_s<<<NB, BS, 0, stream>>>(rowptr, colv, u, g1, v1, w, n);
    k_prop_s<<<NB, BS, 0, stream>>>(rowptr, colv, v1, g2, nullptr, nullptr, n);
    k_layer1<<<(n * 32 + BS - 1) / BS, BS, 0, stream>>>(x, g1, g2, dinv, W1, b1, h, hs16, n);

    // layer 2: fp16 gather -> gA(+gA16); fused gather+layer2+fc -> out
    k_prop_vh<<<(n * 8 + BS - 1) / BS, BS, 0, stream>>>(rowptr, colv, hs16, gA, gA16, n);
    k_prop_fc<<<(n + 31) / 32, BS, 0, stream>>>(rowptr, colv, gA16, h, gA, w, dinv,
                                                W2, b2, Wfc, bfc, out, n);
}

// Round 15
// 271.756 us; speedup vs baseline: 2.2798x; 1.0135x over previous
//
#include <hip/hip_runtime.h>
#include <hip/hip_fp16.h>

// ChebNet K=3. Zero global atomics. fp16 gather operands (fp32 accum).
// r15: gA16 pre-scaled by w[node] at write (kills wsc gather in prop_fc);
//      prop_fc exchange via 8-lane shuffles (LDS 25KB->12.3KB, 8 blocks/CU).

#define BS 256
#define NC 32     // edge-chunk copies
#define NRH 16    // hist node ranges
#define NRB 16    // build node ranges
#define HB 1024
#define RCAP 6250 // ceil(n/16), n <= 100000

__global__ __launch_bounds__(HB) void k_hist32(const int* __restrict__ src,
                                               const int* __restrict__ dst,
                                               int* __restrict__ deg32,
                                               int* __restrict__ cnt32,
                                               int n, int E, int ce) {
    __shared__ int hcnt[RCAP];
    __shared__ int hdeg[RCAP];
    int b = blockIdx.x, c = b & (NC - 1), r = b >> 5;
    int t = threadIdx.x;
    const int R = (n + NRH - 1) / NRH;
    int lo = r * R, hi = min(lo + R, n), len = hi - lo;
    for (int q = t; q < len; q += HB) { hcnt[q] = 0; hdeg[q] = 0; }
    __syncthreads();
    int e0 = c * ce, e1 = min(e0 + ce, E);
    if (e0 < e1) {
        const int4* d4 = reinterpret_cast<const int4*>(dst + e0);
        const int4* s4 = reinterpret_cast<const int4*>(src + e0);
        int L4 = (e1 - e0) >> 2;
        for (int m = 0; m * 4 * HB < L4; ++m) {
            int4 dv[4], sv[4];
            bool ok[4];
            #pragma unroll
            for (int q = 0; q < 4; ++q) {
                int idx = t + (m * 4 + q) * HB;
                ok[q] = idx < L4;
                if (ok[q]) { dv[q] = d4[idx]; sv[q] = s4[idx]; }
            }
            #pragma unroll
            for (int q = 0; q < 4; ++q) if (ok[q]) {
                int d;
                d = dv[q].x; if (d >= lo && d < hi) atomicAdd(&hcnt[d - lo], 1);
                d = dv[q].y; if (d >= lo && d < hi) atomicAdd(&hcnt[d - lo], 1);
                d = dv[q].z; if (d >= lo && d < hi) atomicAdd(&hcnt[d - lo], 1);
                d = dv[q].w; if (d >= lo && d < hi) atomicAdd(&hcnt[d - lo], 1);
                d = sv[q].x; if (d >= lo && d < hi) atomicAdd(&hdeg[d - lo], 1);
                d = sv[q].y; if (d >= lo && d < hi) atomicAdd(&hdeg[d - lo], 1);
                d = sv[q].z; if (d >= lo && d < hi) atomicAdd(&hdeg[d - lo], 1);
                d = sv[q].w; if (d >= lo && d < hi) atomicAdd(&hdeg[d - lo], 1);
            }
        }
        for (int e = e0 + ((e1 - e0) & ~3) + t; e < e1; e += HB) {
            int d = dst[e];
            if (d >= lo && d < hi) atomicAdd(&hcnt[d - lo], 1);
            int s = src[e];
            if (s >= lo && s < hi) atomicAdd(&hdeg[s - lo], 1);
        }
    }
    __syncthreads();
    int base = c * n + lo;
    for (int q = t; q < len; q += HB) {
        cnt32[base + q] = hcnt[q];
        deg32[base + q] = hdeg[q];
    }
}

__global__ void k_dinv32(const int* __restrict__ deg32, const int* __restrict__ cnt32,
                         const float* __restrict__ x, float* __restrict__ dinv,
                         float* __restrict__ u, float* __restrict__ w,
                         int* __restrict__ cnt, int n) {
    int i = blockIdx.x * BS + threadIdx.x;
    if (i < n) {
        int d = 0, ci = 0;
        #pragma unroll
        for (int c = 0; c < NC; ++c) { d += deg32[c * n + i]; ci += cnt32[c * n + i]; }
        float df = (float)d;
        float dv = (d > 0) ? rsqrtf(fmaxf(df, 1.0f)) : 0.0f;
        dinv[i] = dv;
        u[i] = dv * x[i];
        w[i] = -dv * dv;
        cnt[i] = ci;
    }
}

__global__ void k_scan2A(const int* __restrict__ cnt, int* __restrict__ rowptr,
                         int* __restrict__ part, int n) {
    __shared__ int sh[BS];
    int t = threadIdx.x, i = blockIdx.x * BS + t;
    int v = (i < n) ? cnt[i] : 0;
    sh[t] = v; __syncthreads();
    int acc = v;
    for (int d = 1; d < BS; d <<= 1) {
        int add = (t >= d) ? sh[t - d] : 0;
        __syncthreads();
        acc += add; sh[t] = acc;
        __syncthreads();
    }
    if (i < n) rowptr[i] = acc - v;
    if (t == BS - 1) part[blockIdx.x] = acc;
}

__global__ void k_scanB(int* __restrict__ part, int nb) {
    __shared__ int sh[512];
    int t = threadIdx.x;
    int v = (t < nb) ? part[t] : 0;
    sh[t] = v; __syncthreads();
    int acc = v;
    for (int d = 1; d < 512; d <<= 1) {
        int add = (t >= d) ? sh[t - d] : 0;
        __syncthreads();
        acc += add; sh[t] = acc;
        __syncthreads();
    }
    if (t < nb) part[t] = acc - v;
}

__global__ void k_scan2C(int* __restrict__ rowptr, const int* __restrict__ part, int n, int E) {
    int i = blockIdx.x * BS + threadIdx.x;
    if (i < n) rowptr[i] += part[i >> 8];
    if (i == n) rowptr[n] = E;
}

__global__ void k_frag(const int* __restrict__ cnt32, const int* __restrict__ rowptr,
                       int* __restrict__ cur32, int n) {
    int i = blockIdx.x * BS + threadIdx.x;
    if (i < n) {
        int run = rowptr[i];
        #pragma unroll
        for (int c = 0; c < NC; ++c) {
            cur32[c * n + i] = run;
            run += cnt32[c * n + i];
        }
    }
}

__global__ __launch_bounds__(HB) void k_build32(const int* __restrict__ src,
                                                const int* __restrict__ dst,
                                                const int* __restrict__ cur32,
                                                int* __restrict__ colv,
                                                int n, int E, int ce) {
    __shared__ int lcur[RCAP];
    int b = blockIdx.x, r = b & (NRB - 1), c = b >> 4;
    int t = threadIdx.x;
    const int R = (n + NRB - 1) / NRB;
    int lo = r * R, hi = min(lo + R, n), len = hi - lo;
    int base = c * n + lo;
    for (int q = t; q < len; q += HB) lcur[q] = cur32[base + q];
    __syncthreads();
    int e0 = c * ce, e1 = min(e0 + ce, E);
    if (e0 < e1) {
        const int4* d4 = reinterpret_cast<const int4*>(dst + e0);
        const int4* s4 = reinterpret_cast<const int4*>(src + e0);
        int L4 = (e1 - e0) >> 2;
        for (int m = 0; m * 4 * HB < L4; ++m) {
            int4 dv[4], sv[4];
            bool ok[4];
            #pragma unroll
            for (int q = 0; q < 4; ++q) {
                int idx = t + (m * 4 + q) * HB;
                ok[q] = idx < L4;
                if (ok[q]) { dv[q] = d4[idx]; sv[q] = s4[idx]; }
            }
            #pragma unroll
            for (int q = 0; q < 4; ++q) if (ok[q]) {
                int d;
                d = dv[q].x; if (d >= lo && d < hi) { int p = atomicAdd(&lcur[d - lo], 1); colv[p] = sv[q].x; }
                d = dv[q].y; if (d >= lo && d < hi) { int p = atomicAdd(&lcur[d - lo], 1); colv[p] = sv[q].y; }
                d = dv[q].z; if (d >= lo && d < hi) { int p = atomicAdd(&lcur[d - lo], 1); colv[p] = sv[q].z; }
                d = dv[q].w; if (d >= lo && d < hi) { int p = atomicAdd(&lcur[d - lo], 1); colv[p] = sv[q].w; }
            }
        }
        for (int e = e0 + ((e1 - e0) & ~3) + t; e < e1; e += HB) {
            int d = dst[e];
            if (d >= lo && d < hi) { int p = atomicAdd(&lcur[d - lo], 1); colv[p] = src[e]; }
        }
    }
}

__global__ void k_prop_s(const int* __restrict__ rowptr, const int* __restrict__ colv,
                         const float* __restrict__ in, float* __restrict__ g,
                         float* __restrict__ vout, const float* __restrict__ w, int n) {
    int i = blockIdx.x * BS + threadIdx.x;
    if (i >= n) return;
    int b = rowptr[i], e = rowptr[i + 1];
    float s = 0.0f;
    int j = b;
    for (; j + 4 <= e; j += 4) {
        int s0 = colv[j], s1 = colv[j + 1], s2 = colv[j + 2], s3 = colv[j + 3];
        float a0 = in[s0], a1 = in[s1], a2 = in[s2], a3 = in[s3];
        s += (a0 + a1) + (a2 + a3);
    }
    for (; j < e; ++j) s += in[colv[j]];
    g[i] = s;
    if (vout) vout[i] = w[i] * s;
}

// layer1 -> h (fp32, for FC) and hs16 (fp16, gather operand)
__global__ void k_layer1(const float* __restrict__ x, const float* __restrict__ g1,
                         const float* __restrict__ g2, const float* __restrict__ dinv,
                         const float* __restrict__ W1, const float* __restrict__ b1,
                         float* __restrict__ h, __half* __restrict__ hs16, int n) {
    int idx = blockIdx.x * BS + threadIdx.x;
    if (idx < n * 32) {
        int i = idx >> 5, f = idx & 31;
        float x0 = x[i], dv = dinv[i];
        float t1 = -dv * g1[i];
        float t2 = -2.0f * dv * g2[i] - x0;
        float v = x0 * W1[f] + t1 * W1[32 + f] + t2 * W1[64 + f] + b1[f];
        v = fmaxf(v, 0.0f);
        h[idx] = v;
        hs16[idx] = __float2half_rn(dv * v);
    }
}

// fp16 gather: gA fp32 (unscaled) + gA16 fp16 PRE-SCALED by w[node]
__global__ void k_prop_vh(const int* __restrict__ rowptr, const int* __restrict__ colv,
                          const __half* __restrict__ in16, const float* __restrict__ wsc,
                          float* __restrict__ outf, __half* __restrict__ out16, int n) {
    int t = blockIdx.x * BS + threadIdx.x;
    int node = t >> 3;
    if (node >= n) return;
    int ln4 = (t & 7) << 2;
    int b = rowptr[node], e = rowptr[node + 1];
    float4 acc = make_float4(0.f, 0.f, 0.f, 0.f);
    int j = b;
    for (; j + 8 <= e; j += 8) {
        int sx[8];
        #pragma unroll
        for (int q = 0; q < 8; ++q) sx[q] = colv[j + q];
        float2 raw[8];
        #pragma unroll
        for (int q = 0; q < 8; ++q)
            raw[q] = *reinterpret_cast<const float2*>(in16 + (size_t)sx[q] * 32 + ln4);
        #pragma unroll
        for (int q = 0; q < 8; ++q) {
            __half2 p0 = *reinterpret_cast<__half2*>(&raw[q].x);
            __half2 p1 = *reinterpret_cast<__half2*>(&raw[q].y);
            float2 a = __half22float2(p0), c = __half22float2(p1);
            acc.x += a.x; acc.y += a.y; acc.z += c.x; acc.w += c.y;
        }
    }
    for (; j < e; ++j) {
        int s = colv[j];
        float2 raw = *reinterpret_cast<const float2*>(in16 + (size_t)s * 32 + ln4);
        __half2 p0 = *reinterpret_cast<__half2*>(&raw.x);
        __half2 p1 = *reinterpret_cast<__half2*>(&raw.y);
        float2 a = __half22float2(p0), c = __half22float2(p1);
        acc.x += a.x; acc.y += a.y; acc.z += c.x; acc.w += c.y;
    }
    *reinterpret_cast<float4*>(outf + (size_t)node * 32 + ln4) = acc;
    float wn = wsc[node];
    __half2 o0 = __floats2half2_rn(wn * acc.x, wn * acc.y);
    __half2 o1 = __floats2half2_rn(wn * acc.z, wn * acc.w);
    float2 packed;
    *reinterpret_cast<__half2*>(&packed.x) = o0;
    *reinterpret_cast<__half2*>(&packed.y) = o1;
    *reinterpret_cast<float2*>(out16 + (size_t)node * 32 + ln4) = packed;
}

// Fused: gather gB = sum gA16s[s] (pre-scaled) -> shuffle exchange -> layer2 + FC
// 256 threads = 32 nodes x 8 lanes. LDS = W2s only (12 KB).
__global__ __launch_bounds__(BS) void k_prop_fc(
    const int* __restrict__ rowptr, const int* __restrict__ colv,
    const __half* __restrict__ gA16s, const float* __restrict__ h,
    const float* __restrict__ gA, const float* __restrict__ dinv,
    const float* __restrict__ W2, const float* __restrict__ b2,
    const float* __restrict__ Wfc, const float* __restrict__ bfc,
    float* __restrict__ out, int n) {
    __shared__ float W2s[3 * 32 * 32];
    int tid = threadIdx.x;
    for (int q = tid; q < 3 * 32 * 32; q += BS) W2s[q] = W2[q];
    __syncthreads();
    int nd = tid >> 3, ln = tid & 7, ln4 = ln << 2;
    int i = blockIdx.x * 32 + nd;
    if (i >= n) return;
    float4 acc = make_float4(0.f, 0.f, 0.f, 0.f);
    int b = rowptr[i], e = rowptr[i + 1];
    int j = b;
    for (; j + 8 <= e; j += 8) {
        int sx[8];
        #pragma unroll
        for (int q = 0; q < 8; ++q) sx[q] = colv[j + q];
        float2 raw[8];
        #pragma unroll
        for (int q = 0; q < 8; ++q)
            raw[q] = *reinterpret_cast<const float2*>(gA16s + (size_t)sx[q] * 32 + ln4);
        #pragma unroll
        for (int q = 0; q < 8; ++q) {
            __half2 p0 = *reinterpret_cast<__half2*>(&raw[q].x);
            __half2 p1 = *reinterpret_cast<__half2*>(&raw[q].y);
            float2 a = __half22float2(p0), c = __half22float2(p1);
            acc.x += a.x; acc.y += a.y; acc.z += c.x; acc.w += c.y;
        }
    }
    for (; j < e; ++j) {
        int s = colv[j];
        float2 raw = *reinterpret_cast<const float2*>(gA16s + (size_t)s * 32 + ln4);
        __half2 p0 = *reinterpret_cast<__half2*>(&raw.x);
        __half2 p1 = *reinterpret_cast<__half2*>(&raw.y);
        float2 a = __half22float2(p0), c = __half22float2(p1);
        acc.x += a.x; acc.y += a.y; acc.z += c.x; acc.w += c.y;
    }
    // per-lane slices (k = ln4 + j): hk, s1k, s2k
    float dv = dinv[i];
    float4 hv  = *reinterpret_cast<const float4*>(h  + (size_t)i * 32 + ln4);
    float4 gav = *reinterpret_cast<const float4*>(gA + (size_t)i * 32 + ln4);
    float hkv[4] = { hv.x, hv.y, hv.z, hv.w };
    float s1v[4] = { -dv * gav.x, -dv * gav.y, -dv * gav.z, -dv * gav.w };
    float s2v[4] = { -2.0f * dv * acc.x - hv.x, -2.0f * dv * acc.y - hv.y,
                     -2.0f * dv * acc.z - hv.z, -2.0f * dv * acc.w - hv.w };
    float a0 = b2[ln4 + 0], a1 = b2[ln4 + 1], a2 = b2[ln4 + 2], a3 = b2[ln4 + 3];
    #pragma unroll
    for (int k = 0; k < 32; ++k) {
        int srcLn = k >> 2;
        float hk  = __shfl(hkv[k & 3], srcLn, 8);
        float s1k = __shfl(s1v[k & 3], srcLn, 8);
        float s2k = __shfl(s2v[k & 3], srcLn, 8);
        const float* w0 = W2s + k * 32 + ln4;
        a0 += hk * w0[0] + s1k * w0[1024] + s2k * w0[2048];
        a1 += hk * w0[1] + s1k * w0[1025] + s2k * w0[2049];
        a2 += hk * w0[2] + s1k * w0[1026] + s2k * w0[2050];
        a3 += hk * w0[3] + s1k * w0[1027] + s2k * w0[2051];
    }
    float p = fmaxf(a0, 0.f) * Wfc[ln4 + 0] + fmaxf(a1, 0.f) * Wfc[ln4 + 1]
            + fmaxf(a2, 0.f) * Wfc[ln4 + 2] + fmaxf(a3, 0.f) * Wfc[ln4 + 3];
    #pragma unroll
    for (int m = 4; m >= 1; m >>= 1) p += __shfl_xor(p, m, 8);
    if (ln == 0) out[i] = p + bfc[0];
}

extern "C" void kernel_launch(void* const* d_in, const int* in_sizes, int n_in,
                              void* d_out, int out_size, void* d_ws, size_t ws_size,
                              hipStream_t stream) {
    const float* x   = (const float*)d_in[0];
    const int*   ei  = (const int*)d_in[1];
    const float* W1  = (const float*)d_in[2];
    const float* b1  = (const float*)d_in[3];
    const float* W2  = (const float*)d_in[4];
    const float* b2  = (const float*)d_in[5];
    const float* Wfc = (const float*)d_in[6];
    const float* bfc = (const float*)d_in[7];
    float* out = (float*)d_out;

    const int n = in_sizes[0];
    const int E = in_sizes[1] / 2;
    const int* src = ei;
    const int* dst = ei + E;
    const int ce = (((E + NC - 1) / NC) + 3) & ~3;

    // workspace (4B words). R1=h/cnt32 (32n), R2=[hs16 16n | gA16s 16n]/cur32 (32n),
    // R3=gA/deg32 (32n).
    int*   cnt    = (int*)d_ws;                  // n
    int*   rowptr = cnt + n;                     // n+4
    int*   part   = rowptr + n + 4;              // 512
    float* dinv   = (float*)(part + 512);        // n
    float* u      = dinv + n;                    // n
    float* w      = u + n;                       // n
    float* g1     = w + n;                       // n
    float* v1     = g1 + n;                      // n
    float* g2     = v1 + n;                      // n
    int*   colv   = (int*)(g2 + n);              // E
    float* h      = (float*)(colv + E);          // 32n (R1)
    float* R2     = h + (size_t)32 * n;          // 32n
    float* gA     = R2 + (size_t)32 * n;         // 32n (R3)
    __half* hs16  = (__half*)R2;                    // 32n halfs = 16n words
    __half* gA16s = (__half*)(R2 + (size_t)16 * n); // 32n halfs = 16n words
    int*   cnt32  = (int*)h;                     // dead before k_layer1 writes h
    int*   cur32  = (int*)R2;                    // dead before k_layer1 writes hs16
    int*   deg32  = (int*)gA;                    // dead before k_prop_vh writes gA

    const int NB = (n + BS - 1) / BS;

    k_hist32<<<NC * NRH, HB, 0, stream>>>(src, dst, deg32, cnt32, n, E, ce);
    k_dinv32<<<NB, BS, 0, stream>>>(deg32, cnt32, x, dinv, u, w, cnt, n);
    k_scan2A<<<NB, BS, 0, stream>>>(cnt, rowptr, part, n);
    k_scanB<<<1, 512, 0, stream>>>(part, NB);
    k_scan2C<<<NB + 1, BS, 0, stream>>>(rowptr, part, n, E);
    k_frag<<<NB, BS, 0, stream>>>(cnt32, rowptr, cur32, n);
    k_build32<<<NC * NRB, HB, 0, stream>>>(src, dst, cur32, colv, n, E, ce);

    // layer 1 (scalar)
    k_prop_s<<<NB, BS, 0, stream>>>(rowptr, colv, u, g1, v1, w, n);
    k_prop_s<<<NB, BS, 0, stream>>>(rowptr, colv, v1, g2, nullptr, nullptr, n);
    k_layer1<<<(n * 32 + BS - 1) / BS, BS, 0, stream>>>(x, g1, g2, dinv, W1, b1, h, hs16, n);

    // layer 2: fp16 gather -> gA (fp32) + gA16s (pre-scaled); fused gather+layer2+fc
    k_prop_vh<<<(n * 8 + BS - 1) / BS, BS, 0, stream>>>(rowptr, colv, hs16, w, gA, gA16s, n);
    k_prop_fc<<<(n + 31) / 32, BS, 0, stream>>>(rowptr, colv, gA16s, h, gA, dinv,
                                                W2, b2, Wfc, bfc, out, n);
}

// Round 16
// 269.573 us; speedup vs baseline: 2.2983x; 1.0081x over previous
//
#include <hip/hip_runtime.h>
#include <hip/hip_fp16.h>

// ChebNet K=3. Zero global atomics. fp16 gather operands (fp32 accum).
// r16: fp32 gA eliminated (s1 reconstructed as gA16s/dinv since gA16s = -dinv^2*gA);
//      gather kernels use 4 lanes/node x 16B/lane (coalescing sweet spot).

#define BS 256
#define NC 32     // edge-chunk copies
#define NRH 16    // hist node ranges
#define NRB 16    // build node ranges
#define HB 1024
#define RCAP 6250 // ceil(n/16), n <= 100000

__global__ __launch_bounds__(HB) void k_hist32(const int* __restrict__ src,
                                               const int* __restrict__ dst,
                                               int* __restrict__ deg32,
                                               int* __restrict__ cnt32,
                                               int n, int E, int ce) {
    __shared__ int hcnt[RCAP];
    __shared__ int hdeg[RCAP];
    int b = blockIdx.x, c = b & (NC - 1), r = b >> 5;
    int t = threadIdx.x;
    const int R = (n + NRH - 1) / NRH;
    int lo = r * R, hi = min(lo + R, n), len = hi - lo;
    for (int q = t; q < len; q += HB) { hcnt[q] = 0; hdeg[q] = 0; }
    __syncthreads();
    int e0 = c * ce, e1 = min(e0 + ce, E);
    if (e0 < e1) {
        const int4* d4 = reinterpret_cast<const int4*>(dst + e0);
        const int4* s4 = reinterpret_cast<const int4*>(src + e0);
        int L4 = (e1 - e0) >> 2;
        for (int m = 0; m * 4 * HB < L4; ++m) {
            int4 dv[4], sv[4];
            bool ok[4];
            #pragma unroll
            for (int q = 0; q < 4; ++q) {
                int idx = t + (m * 4 + q) * HB;
                ok[q] = idx < L4;
                if (ok[q]) { dv[q] = d4[idx]; sv[q] = s4[idx]; }
            }
            #pragma unroll
            for (int q = 0; q < 4; ++q) if (ok[q]) {
                int d;
                d = dv[q].x; if (d >= lo && d < hi) atomicAdd(&hcnt[d - lo], 1);
                d = dv[q].y; if (d >= lo && d < hi) atomicAdd(&hcnt[d - lo], 1);
                d = dv[q].z; if (d >= lo && d < hi) atomicAdd(&hcnt[d - lo], 1);
                d = dv[q].w; if (d >= lo && d < hi) atomicAdd(&hcnt[d - lo], 1);
                d = sv[q].x; if (d >= lo && d < hi) atomicAdd(&hdeg[d - lo], 1);
                d = sv[q].y; if (d >= lo && d < hi) atomicAdd(&hdeg[d - lo], 1);
                d = sv[q].z; if (d >= lo && d < hi) atomicAdd(&hdeg[d - lo], 1);
                d = sv[q].w; if (d >= lo && d < hi) atomicAdd(&hdeg[d - lo], 1);
            }
        }
        for (int e = e0 + ((e1 - e0) & ~3) + t; e < e1; e += HB) {
            int d = dst[e];
            if (d >= lo && d < hi) atomicAdd(&hcnt[d - lo], 1);
            int s = src[e];
            if (s >= lo && s < hi) atomicAdd(&hdeg[s - lo], 1);
        }
    }
    __syncthreads();
    int base = c * n + lo;
    for (int q = t; q < len; q += HB) {
        cnt32[base + q] = hcnt[q];
        deg32[base + q] = hdeg[q];
    }
}

__global__ void k_dinv32(const int* __restrict__ deg32, const int* __restrict__ cnt32,
                         const float* __restrict__ x, float* __restrict__ dinv,
                         float* __restrict__ u, float* __restrict__ w,
                         int* __restrict__ cnt, int n) {
    int i = blockIdx.x * BS + threadIdx.x;
    if (i < n) {
        int d = 0, ci = 0;
        #pragma unroll
        for (int c = 0; c < NC; ++c) { d += deg32[c * n + i]; ci += cnt32[c * n + i]; }
        float df = (float)d;
        float dv = (d > 0) ? rsqrtf(fmaxf(df, 1.0f)) : 0.0f;
        dinv[i] = dv;
        u[i] = dv * x[i];
        w[i] = -dv * dv;
        cnt[i] = ci;
    }
}

__global__ void k_scan2A(const int* __restrict__ cnt, int* __restrict__ rowptr,
                         int* __restrict__ part, int n) {
    __shared__ int sh[BS];
    int t = threadIdx.x, i = blockIdx.x * BS + t;
    int v = (i < n) ? cnt[i] : 0;
    sh[t] = v; __syncthreads();
    int acc = v;
    for (int d = 1; d < BS; d <<= 1) {
        int add = (t >= d) ? sh[t - d] : 0;
        __syncthreads();
        acc += add; sh[t] = acc;
        __syncthreads();
    }
    if (i < n) rowptr[i] = acc - v;
    if (t == BS - 1) part[blockIdx.x] = acc;
}

__global__ void k_scanB(int* __restrict__ part, int nb) {
    __shared__ int sh[512];
    int t = threadIdx.x;
    int v = (t < nb) ? part[t] : 0;
    sh[t] = v; __syncthreads();
    int acc = v;
    for (int d = 1; d < 512; d <<= 1) {
        int add = (t >= d) ? sh[t - d] : 0;
        __syncthreads();
        acc += add; sh[t] = acc;
        __syncthreads();
    }
    if (t < nb) part[t] = acc - v;
}

__global__ void k_scan2C(int* __restrict__ rowptr, const int* __restrict__ part, int n, int E) {
    int i = blockIdx.x * BS + threadIdx.x;
    if (i < n) rowptr[i] += part[i >> 8];
    if (i == n) rowptr[n] = E;
}

__global__ void k_frag(const int* __restrict__ cnt32, const int* __restrict__ rowptr,
                       int* __restrict__ cur32, int n) {
    int i = blockIdx.x * BS + threadIdx.x;
    if (i < n) {
        int run = rowptr[i];
        #pragma unroll
        for (int c = 0; c < NC; ++c) {
            cur32[c * n + i] = run;
            run += cnt32[c * n + i];
        }
    }
}

__global__ __launch_bounds__(HB) void k_build32(const int* __restrict__ src,
                                                const int* __restrict__ dst,
                                                const int* __restrict__ cur32,
                                                int* __restrict__ colv,
                                                int n, int E, int ce) {
    __shared__ int lcur[RCAP];
    int b = blockIdx.x, r = b & (NRB - 1), c = b >> 4;
    int t = threadIdx.x;
    const int R = (n + NRB - 1) / NRB;
    int lo = r * R, hi = min(lo + R, n), len = hi - lo;
    int base = c * n + lo;
    for (int q = t; q < len; q += HB) lcur[q] = cur32[base + q];
    __syncthreads();
    int e0 = c * ce, e1 = min(e0 + ce, E);
    if (e0 < e1) {
        const int4* d4 = reinterpret_cast<const int4*>(dst + e0);
        const int4* s4 = reinterpret_cast<const int4*>(src + e0);
        int L4 = (e1 - e0) >> 2;
        for (int m = 0; m * 4 * HB < L4; ++m) {
            int4 dv[4], sv[4];
            bool ok[4];
            #pragma unroll
            for (int q = 0; q < 4; ++q) {
                int idx = t + (m * 4 + q) * HB;
                ok[q] = idx < L4;
                if (ok[q]) { dv[q] = d4[idx]; sv[q] = s4[idx]; }
            }
            #pragma unroll
            for (int q = 0; q < 4; ++q) if (ok[q]) {
                int d;
                d = dv[q].x; if (d >= lo && d < hi) { int p = atomicAdd(&lcur[d - lo], 1); colv[p] = sv[q].x; }
                d = dv[q].y; if (d >= lo && d < hi) { int p = atomicAdd(&lcur[d - lo], 1); colv[p] = sv[q].y; }
                d = dv[q].z; if (d >= lo && d < hi) { int p = atomicAdd(&lcur[d - lo], 1); colv[p] = sv[q].z; }
                d = dv[q].w; if (d >= lo && d < hi) { int p = atomicAdd(&lcur[d - lo], 1); colv[p] = sv[q].w; }
            }
        }
        for (int e = e0 + ((e1 - e0) & ~3) + t; e < e1; e += HB) {
            int d = dst[e];
            if (d >= lo && d < hi) { int p = atomicAdd(&lcur[d - lo], 1); colv[p] = src[e]; }
        }
    }
}

__global__ void k_prop_s(const int* __restrict__ rowptr, const int* __restrict__ colv,
                         const float* __restrict__ in, float* __restrict__ g,
                         float* __restrict__ vout, const float* __restrict__ w, int n) {
    int i = blockIdx.x * BS + threadIdx.x;
    if (i >= n) return;
    int b = rowptr[i], e = rowptr[i + 1];
    float s = 0.0f;
    int j = b;
    for (; j + 4 <= e; j += 4) {
        int s0 = colv[j], s1 = colv[j + 1], s2 = colv[j + 2], s3 = colv[j + 3];
        float a0 = in[s0], a1 = in[s1], a2 = in[s2], a3 = in[s3];
        s += (a0 + a1) + (a2 + a3);
    }
    for (; j < e; ++j) s += in[colv[j]];
    g[i] = s;
    if (vout) vout[i] = w[i] * s;
}

// layer1 -> h (fp32, for FC) and hs16 (fp16, gather operand)
__global__ void k_layer1(const float* __restrict__ x, const float* __restrict__ g1,
                         const float* __restrict__ g2, const float* __restrict__ dinv,
                         const float* __restrict__ W1, const float* __restrict__ b1,
                         float* __restrict__ h, __half* __restrict__ hs16, int n) {
    int idx = blockIdx.x * BS + threadIdx.x;
    if (idx < n * 32) {
        int i = idx >> 5, f = idx & 31;
        float x0 = x[i], dv = dinv[i];
        float t1 = -dv * g1[i];
        float t2 = -2.0f * dv * g2[i] - x0;
        float v = x0 * W1[f] + t1 * W1[32 + f] + t2 * W1[64 + f] + b1[f];
        v = fmaxf(v, 0.0f);
        h[idx] = v;
        hs16[idx] = __float2half_rn(dv * v);
    }
}

// fp16 gather, 4 lanes/node x 8 halfs (16B) per lane, 8 edges in flight.
// Writes ONLY gA16s = w[node] * (gathered sum), fp16.
__global__ void k_prop_vh(const int* __restrict__ rowptr, const int* __restrict__ colv,
                          const __half* __restrict__ in16, const float* __restrict__ wsc,
                          __half* __restrict__ out16, int n) {
    int t = blockIdx.x * BS + threadIdx.x;
    int node = t >> 2;
    if (node >= n) return;
    int ln8 = (t & 3) << 3;
    int b = rowptr[node], e = rowptr[node + 1];
    float acc[8] = {0.f, 0.f, 0.f, 0.f, 0.f, 0.f, 0.f, 0.f};
    int j = b;
    for (; j + 8 <= e; j += 8) {
        int sx[8];
        #pragma unroll
        for (int q = 0; q < 8; ++q) sx[q] = colv[j + q];
        float4 raw[8];
        #pragma unroll
        for (int q = 0; q < 8; ++q)
            raw[q] = *reinterpret_cast<const float4*>(in16 + (size_t)sx[q] * 32 + ln8);
        #pragma unroll
        for (int q = 0; q < 8; ++q) {
            const __half2* hp = reinterpret_cast<const __half2*>(&raw[q]);
            #pragma unroll
            for (int d = 0; d < 4; ++d) {
                float2 f = __half22float2(hp[d]);
                acc[2 * d] += f.x; acc[2 * d + 1] += f.y;
            }
        }
    }
    for (; j < e; ++j) {
        int s = colv[j];
        float4 raw = *reinterpret_cast<const float4*>(in16 + (size_t)s * 32 + ln8);
        const __half2* hp = reinterpret_cast<const __half2*>(&raw);
        #pragma unroll
        for (int d = 0; d < 4; ++d) {
            float2 f = __half22float2(hp[d]);
            acc[2 * d] += f.x; acc[2 * d + 1] += f.y;
        }
    }
    float wn = wsc[node];
    float4 pk;
    __half2* op = reinterpret_cast<__half2*>(&pk);
    #pragma unroll
    for (int d = 0; d < 4; ++d)
        op[d] = __floats2half2_rn(wn * acc[2 * d], wn * acc[2 * d + 1]);
    *reinterpret_cast<float4*>(out16 + (size_t)node * 32 + ln8) = pk;
}

// Fused: gather gB = sum gA16s[s] (pre-scaled); s1 = gA16s[i]/dinv[i]; shuffle matvec + FC.
// 256 threads = 64 nodes x 4 lanes. LDS = W2s only (12 KB).
__global__ __launch_bounds__(BS) void k_prop_fc(
    const int* __restrict__ rowptr, const int* __restrict__ colv,
    const __half* __restrict__ gA16s, const float* __restrict__ h,
    const float* __restrict__ dinv, const float* __restrict__ W2,
    const float* __restrict__ b2, const float* __restrict__ Wfc,
    const float* __restrict__ bfc, float* __restrict__ out, int n) {
    __shared__ float W2s[3 * 32 * 32];
    int tid = threadIdx.x;
    for (int q = tid; q < 3 * 32 * 32; q += BS) W2s[q] = W2[q];
    __syncthreads();
    int nd = tid >> 2, ln = tid & 3, ln8 = ln << 3;
    int i = blockIdx.x * 64 + nd;
    if (i >= n) return;
    float acc[8] = {0.f, 0.f, 0.f, 0.f, 0.f, 0.f, 0.f, 0.f};
    int b = rowptr[i], e = rowptr[i + 1];
    int j = b;
    for (; j + 8 <= e; j += 8) {
        int sx[8];
        #pragma unroll
        for (int q = 0; q < 8; ++q) sx[q] = colv[j + q];
        float4 raw[8];
        #pragma unroll
        for (int q = 0; q < 8; ++q)
            raw[q] = *reinterpret_cast<const float4*>(gA16s + (size_t)sx[q] * 32 + ln8);
        #pragma unroll
        for (int q = 0; q < 8; ++q) {
            const __half2* hp = reinterpret_cast<const __half2*>(&raw[q]);
            #pragma unroll
            for (int d = 0; d < 4; ++d) {
                float2 f = __half22float2(hp[d]);
                acc[2 * d] += f.x; acc[2 * d + 1] += f.y;
            }
        }
    }
    for (; j < e; ++j) {
        int s = colv[j];
        float4 raw = *reinterpret_cast<const float4*>(gA16s + (size_t)s * 32 + ln8);
        const __half2* hp = reinterpret_cast<const __half2*>(&raw);
        #pragma unroll
        for (int d = 0; d < 4; ++d) {
            float2 f = __half22float2(hp[d]);
            acc[2 * d] += f.x; acc[2 * d + 1] += f.y;
        }
    }
    // own-row terms: s1 = gA16s[i]/dv (since gA16s = -dv^2 * gA), s2 = -2dv*gB - h
    float dv = dinv[i];
    float rdv = (dv > 0.0f) ? (1.0f / dv) : 0.0f;
    float4 gaw = *reinterpret_cast<const float4*>(gA16s + (size_t)i * 32 + ln8);
    const __half2* gp = reinterpret_cast<const __half2*>(&gaw);
    float4 hv0 = *reinterpret_cast<const float4*>(h + (size_t)i * 32 + ln8);
    float4 hv1 = *reinterpret_cast<const float4*>(h + (size_t)i * 32 + ln8 + 4);
    float hkv[8] = { hv0.x, hv0.y, hv0.z, hv0.w, hv1.x, hv1.y, hv1.z, hv1.w };
    float s1v[8], s2v[8];
    #pragma unroll
    for (int d = 0; d < 4; ++d) {
        float2 g = __half22float2(gp[d]);
        s1v[2 * d] = g.x * rdv; s1v[2 * d + 1] = g.y * rdv;
    }
    #pragma unroll
    for (int q = 0; q < 8; ++q) s2v[q] = -2.0f * dv * acc[q] - hkv[q];
    float a[8];
    #pragma unroll
    for (int q = 0; q < 8; ++q) a[q] = b2[ln8 + q];
    #pragma unroll
    for (int k = 0; k < 32; ++k) {
        int srcLn = k >> 3;
        float hk  = __shfl(hkv[k & 7], srcLn, 4);
        float s1k = __shfl(s1v[k & 7], srcLn, 4);
        float s2k = __shfl(s2v[k & 7], srcLn, 4);
        const float* w0 = W2s + k * 32 + ln8;
        #pragma unroll
        for (int q = 0; q < 8; ++q)
            a[q] += hk * w0[q] + s1k * w0[1024 + q] + s2k * w0[2048 + q];
    }
    float p = 0.0f;
    #pragma unroll
    for (int q = 0; q < 8; ++q) p += fmaxf(a[q], 0.0f) * Wfc[ln8 + q];
    p += __shfl_xor(p, 1, 4);
    p += __shfl_xor(p, 2, 4);
    if (ln == 0) out[i] = p + bfc[0];
}

extern "C" void kernel_launch(void* const* d_in, const int* in_sizes, int n_in,
                              void* d_out, int out_size, void* d_ws, size_t ws_size,
                              hipStream_t stream) {
    const float* x   = (const float*)d_in[0];
    const int*   ei  = (const int*)d_in[1];
    const float* W1  = (const float*)d_in[2];
    const float* b1  = (const float*)d_in[3];
    const float* W2  = (const float*)d_in[4];
    const float* b2  = (const float*)d_in[5];
    const float* Wfc = (const float*)d_in[6];
    const float* bfc = (const float*)d_in[7];
    float* out = (float*)d_out;

    const int n = in_sizes[0];
    const int E = in_sizes[1] / 2;
    const int* src = ei;
    const int* dst = ei + E;
    const int ce = (((E + NC - 1) / NC) + 3) & ~3;

    // workspace (4B words). R1=h/cnt32 (32n), R2=[hs16 16n | gA16s 16n]/cur32 (32n),
    // R3=deg32 (32n).
    int*   cnt    = (int*)d_ws;                  // n
    int*   rowptr = cnt + n;                     // n+4
    int*   part   = rowptr + n + 4;              // 512
    float* dinv   = (float*)(part + 512);        // n
    float* u      = dinv + n;                    // n
    float* w      = u + n;                       // n
    float* g1     = w + n;                       // n
    float* v1     = g1 + n;                      // n
    float* g2     = v1 + n;                      // n
    int*   colv   = (int*)(g2 + n);              // E
    float* h      = (float*)(colv + E);          // 32n (R1)
    float* R2     = h + (size_t)32 * n;          // 32n
    float* R3     = R2 + (size_t)32 * n;         // 32n
    __half* hs16  = (__half*)R2;                    // 32n halfs = 16n words
    __half* gA16s = (__half*)(R2 + (size_t)16 * n); // 32n halfs = 16n words
    int*   cnt32  = (int*)h;                     // dead before k_layer1 writes h
    int*   cur32  = (int*)R2;                    // dead before k_layer1 writes hs16
    int*   deg32  = (int*)R3;                    // only user of R3

    const int NB = (n + BS - 1) / BS;

    k_hist32<<<NC * NRH, HB, 0, stream>>>(src, dst, deg32, cnt32, n, E, ce);
    k_dinv32<<<NB, BS, 0, stream>>>(deg32, cnt32, x, dinv, u, w, cnt, n);
    k_scan2A<<<NB, BS, 0, stream>>>(cnt, rowptr, part, n);
    k_scanB<<<1, 512, 0, stream>>>(part, NB);
    k_scan2C<<<NB + 1, BS, 0, stream>>>(rowptr, part, n, E);
    k_frag<<<NB, BS, 0, stream>>>(cnt32, rowptr, cur32, n);
    k_build32<<<NC * NRB, HB, 0, stream>>>(src, dst, cur32, colv, n, E, ce);

    // layer 1 (scalar)
    k_prop_s<<<NB, BS, 0, stream>>>(rowptr, colv, u, g1, v1, w, n);
    k_prop_s<<<NB, BS, 0, stream>>>(rowptr, colv, v1, g2, nullptr, nullptr, n);
    k_layer1<<<(n * 32 + BS - 1) / BS, BS, 0, stream>>>(x, g1, g2, dinv, W1, b1, h, hs16, n);

    // layer 2: fp16 gather -> gA16s (pre-scaled, only artifact); fused gather+layer2+fc
    k_prop_vh<<<(n * 4 + BS - 1) / BS, BS, 0, stream>>>(rowptr, colv, hs16, w, gA16s, n);
    k_prop_fc<<<(n + 63) / 64, BS, 0, stream>>>(rowptr, colv, gA16s, h, dinv,
                                                W2, b2, Wfc, bfc, out, n);
}